// Round 7
// baseline (370.474 us; speedup 1.0000x reference)
//
#include <hip/hip_runtime.h>
#include <hip/hip_bf16.h>
#include <math.h>

#define BNROWS (4096*32)   // 131072
#define RB     64          // rows per MLP block
#define LN32   3.4657359027997265f

typedef __attribute__((ext_vector_type(8))) short bf16x8;
typedef __attribute__((ext_vector_type(4))) float f32x4;

static __device__ __forceinline__ ushort f2bf(float x) {
    union { __hip_bfloat16 h; ushort u; } cv;
    cv.h = __float2bfloat16(x);
    return cv.u;
}

// ---------------------------------------------------------------------------
// Merged prep: blocks [0,8192) convert obs f32->bf16; blocks [8192,8270) pack
// weights into MFMA fragment order. Saves one launch vs separate kernels.
__global__ void prep_all(const float* __restrict__ obs,
                         ushort* __restrict__ obs_bf,
                         const float* __restrict__ w1,
                         const float* __restrict__ w2,
                         ushort* __restrict__ pB1, ushort* __restrict__ pB2,
                         ushort* __restrict__ pB3, ushort* __restrict__ pB4) {
    if (blockIdx.x < 8192) {
        size_t i = ((size_t)blockIdx.x * 256 + threadIdx.x) * 4;
        float4 v = *(const float4*)&obs[i];
        ushort4 o;
        o.x = f2bf(v.x); o.y = f2bf(v.y); o.z = f2bf(v.z); o.w = f2bf(v.w);
        *(ushort4*)&obs_bf[i] = o;
        return;
    }
    int g = (blockIdx.x - 8192) * 256 + threadIdx.x;   // 19968 total
    ushort out[8];
    ushort* dst;
    if (g < 3072) {
        int lane = g & 63, gc = g >> 6;
        int t = gc / 3, c = gc % 3;
        int m = lane & 15, q = lane >> 4, n = t * 16 + m;
        #pragma unroll
        for (int j = 0; j < 8; ++j) {
            int k = c * 32 + q * 8 + j;
            out[j] = f2bf((k < 80) ? w1[k * 256 + n] : 0.f);
        }
        dst = &pB1[g * 8];
    } else if (g < 11264) {
        int gg = g - 3072;
        int lane = gg & 63, gc = gg >> 6;
        int t = gc >> 3, c = gc & 7;
        int m = lane & 15, q = lane >> 4, n = t * 16 + m;
        #pragma unroll
        for (int j = 0; j < 8; ++j)
            out[j] = f2bf(w2[(c * 32 + q * 8 + j) * 256 + n]);
        dst = &pB2[gg * 8];
    } else if (g < 19456) {
        int gg = g - 11264;
        int lane = gg & 63, gc = gg >> 6;
        int t = gc >> 3, c = gc & 7;
        int m = lane & 15, q = lane >> 4;
        #pragma unroll
        for (int j = 0; j < 8; ++j)
            out[j] = f2bf(w2[(t * 16 + m) * 256 + c * 32 + q * 8 + j]);
        dst = &pB3[gg * 8];
    } else if (g < 19968) {
        int gg = g - 19456;
        int lane = gg & 63, c = gg >> 6;
        int m = lane & 15, q = lane >> 4;
        #pragma unroll
        for (int j = 0; j < 8; ++j)
            out[j] = f2bf(w1[(64 + m) * 256 + c * 32 + q * 8 + j]);
        dst = &pB4[gg * 8];
    } else return;
    *(uint4*)dst = *(uint4*)out;
}

// ---------------------------------------------------------------------------
// mlp v2 (round 7): fragment-order LDS. Producer epilogues write each h1/dz2/
// dz1 value to the exact address its consumer lane reads, so every MFMA-
// feeding ds_read is lane-contiguous 16B (conflict-free by construction,
// base + imm-offset addressing). obs fragments come straight from global
// (L2/L3-resident); 'a' staged once into tiny fragment-order BaF (covers the
// zero-pad); biases read as 16B global broadcasts. LDS 38912 B -> 4 blocks/CU
// (32 waves, was 24). Producer->consumer map for tile = w*2+tc, lane (m,q):
//   kblk = tile>>1, koff = (tile&1)*16 + q*4, q' = koff>>3, j0 = koff&7
//   AF[((rt*8 + kblk)*64 + q'*16 + m)*8 + j0]  (ushort4 store, <=4-way)
__global__ __launch_bounds__(512) void mlp_mfma(
    const ushort* __restrict__ obs_bf,  // [BN,64] bf16
    const float* __restrict__ a_in,     // [BN,16]
    const float* __restrict__ b1,       // [256]
    const float* __restrict__ b2,       // [256]
    const float* __restrict__ w3,       // [256]
    const float* __restrict__ b3,       // [1]
    const ushort* __restrict__ pB1, const ushort* __restrict__ pB2,
    const ushort* __restrict__ pB3, const ushort* __restrict__ pB4,
    float* __restrict__ score,          // [BN,16]
    float* __restrict__ qout,           // [BN]
    int wantq)
{
    __shared__ __align__(16) ushort AF[4 * 8 * 64 * 8];   // 32768 B: h1->dz2->dz1
    __shared__ __align__(16) ushort BaF[4 * 64 * 8];      // 4096 B: a-fragments (c=2)
    __shared__ float qpart[8][RB];                        // 2048 B

    const int tid  = threadIdx.x;
    const int row0 = blockIdx.x * RB;
    const int lane = tid & 63;
    const int w    = tid >> 6;        // wave 0..7 -> col-tiles {2w, 2w+1}
    const int m    = lane & 15;
    const int q    = lane >> 4;

    // ---- Phase A (tiny): a -> bf16 fragments into BaF; q'=2,3 region zeroed.
    if (tid < 256) {
        int r = tid >> 2, d0 = (tid & 3) * 4;       // a cols d0..d0+3
        int rt = r >> 4, mm = r & 15;
        float4 av = *(const float4*)&a_in[(size_t)(row0 + r) * 16 + d0];
        ushort4 pv;
        pv.x = f2bf(av.x); pv.y = f2bf(av.y); pv.z = f2bf(av.z); pv.w = f2bf(av.w);
        int qp_ = d0 >> 3, j0 = d0 & 7;
        *(ushort4*)&BaF[((rt * 64 + qp_ * 16 + mm) << 3) + j0] = pv;
        ushort4 zv; zv.x = zv.y = zv.z = zv.w = 0;
        *(ushort4*)&BaF[((rt * 64 + (2 + qp_) * 16 + mm) << 3) + j0] = zv;
    }
    __syncthreads();                                       // (1)

    f32x4 acc[4][2];                  // [row-tile][col-tile-in-wave]
    unsigned relumask = 0u;           // 32 bits: rt*8 + tc*4 + i

    // ---- Phase B: z1 = h0 @ w1 (+b1) ; relu -> AF ; mask -> regs
    #pragma unroll
    for (int tc = 0; tc < 2; ++tc)
        #pragma unroll
        for (int rt = 0; rt < 4; ++rt) acc[rt][tc] = (f32x4){0.f, 0.f, 0.f, 0.f};
    #pragma unroll
    for (int c = 0; c < 2; ++c) {     // obs fragments straight from global
        bf16x8 af[4];
        #pragma unroll
        for (int rt = 0; rt < 4; ++rt)
            af[rt] = *(const bf16x8*)&obs_bf[(size_t)(row0 + rt * 16 + m) * 64 + c * 32 + q * 8];
        #pragma unroll
        for (int tc = 0; tc < 2; ++tc) {
            bf16x8 wfr = *(const bf16x8*)&pB1[(((w * 2 + tc) * 3 + c) * 64 + lane) * 8];
            #pragma unroll
            for (int rt = 0; rt < 4; ++rt)
                acc[rt][tc] = __builtin_amdgcn_mfma_f32_16x16x32_bf16(wfr, af[rt], acc[rt][tc], 0, 0, 0);
        }
    }
    {                                  // c = 2: a-fragments (zero-padded) from BaF
        bf16x8 af[4];
        #pragma unroll
        for (int rt = 0; rt < 4; ++rt)
            af[rt] = *(const bf16x8*)&BaF[(rt * 64 + lane) * 8];
        #pragma unroll
        for (int tc = 0; tc < 2; ++tc) {
            bf16x8 wfr = *(const bf16x8*)&pB1[(((w * 2 + tc) * 3 + 2) * 64 + lane) * 8];
            #pragma unroll
            for (int rt = 0; rt < 4; ++rt)
                acc[rt][tc] = __builtin_amdgcn_mfma_f32_16x16x32_bf16(wfr, af[rt], acc[rt][tc], 0, 0, 0);
        }
    }
    #pragma unroll
    for (int tc = 0; tc < 2; ++tc) {
        const int tile = w * 2 + tc;
        const int kblk = tile >> 1;
        const int koff = ((tile & 1) << 4) + q * 4;
        const int qp_  = koff >> 3, j0 = koff & 7;
        const float4 bv = *(const float4*)&b1[tile * 16 + q * 4];
        const float bva[4] = {bv.x, bv.y, bv.z, bv.w};
        #pragma unroll
        for (int rt = 0; rt < 4; ++rt) {
            ushort4 pk;
            float z0 = acc[rt][tc][0] + bva[0];
            float z1 = acc[rt][tc][1] + bva[1];
            float z2 = acc[rt][tc][2] + bva[2];
            float z3 = acc[rt][tc][3] + bva[3];
            if (z0 > 0.f) relumask |= 1u << (rt * 8 + tc * 4 + 0);
            if (z1 > 0.f) relumask |= 1u << (rt * 8 + tc * 4 + 1);
            if (z2 > 0.f) relumask |= 1u << (rt * 8 + tc * 4 + 2);
            if (z3 > 0.f) relumask |= 1u << (rt * 8 + tc * 4 + 3);
            pk.x = f2bf(fmaxf(z0, 0.f)); pk.y = f2bf(fmaxf(z1, 0.f));
            pk.z = f2bf(fmaxf(z2, 0.f)); pk.w = f2bf(fmaxf(z3, 0.f));
            *(ushort4*)&AF[(((rt * 8 + kblk) * 64 + qp_ * 16 + m) << 3) + j0] = pk;
        }
    }
    __syncthreads();                                       // (2)

    // ---- Phase C: z2 = h1 @ w2 (+b2) ; q partials (wantq) ; dz2 -> AF
    #pragma unroll
    for (int tc = 0; tc < 2; ++tc)
        #pragma unroll
        for (int rt = 0; rt < 4; ++rt) acc[rt][tc] = (f32x4){0.f, 0.f, 0.f, 0.f};
    for (int c = 0; c < 8; ++c) {
        bf16x8 af[4];
        #pragma unroll
        for (int rt = 0; rt < 4; ++rt)
            af[rt] = *(const bf16x8*)&AF[((rt * 8 + c) * 64 + lane) * 8];
        #pragma unroll
        for (int tc = 0; tc < 2; ++tc) {
            bf16x8 wfr = *(const bf16x8*)&pB2[(((w * 2 + tc) * 8 + c) * 64 + lane) * 8];
            #pragma unroll
            for (int rt = 0; rt < 4; ++rt)
                acc[rt][tc] = __builtin_amdgcn_mfma_f32_16x16x32_bf16(wfr, af[rt], acc[rt][tc], 0, 0, 0);
        }
    }
    __syncthreads();                                       // (3)
    {
        float qp[4] = {0.f, 0.f, 0.f, 0.f};
        #pragma unroll
        for (int tc = 0; tc < 2; ++tc) {
            const int tile = w * 2 + tc;
            const int kblk = tile >> 1;
            const int koff = ((tile & 1) << 4) + q * 4;
            const int qp_  = koff >> 3, j0 = koff & 7;
            const float4 bv = *(const float4*)&b2[tile * 16 + q * 4];
            const float4 wv = *(const float4*)&w3[tile * 16 + q * 4];
            const float bva[4] = {bv.x, bv.y, bv.z, bv.w};
            const float wva[4] = {wv.x, wv.y, wv.z, wv.w};
            #pragma unroll
            for (int rt = 0; rt < 4; ++rt) {
                ushort4 pk; float dz[4];
                #pragma unroll
                for (int i = 0; i < 4; ++i) {
                    float z = acc[rt][tc][i] + bva[i];
                    if (z > 0.f) { qp[rt] += z * wva[i]; dz[i] = wva[i]; }
                    else         { dz[i] = 0.f; }
                }
                pk.x = f2bf(dz[0]); pk.y = f2bf(dz[1]);
                pk.z = f2bf(dz[2]); pk.w = f2bf(dz[3]);
                *(ushort4*)&AF[(((rt * 8 + kblk) * 64 + qp_ * 16 + m) << 3) + j0] = pk;
            }
        }
        if (wantq) {
            #pragma unroll
            for (int rt = 0; rt < 4; ++rt) {
                float v = qp[rt];
                v += __shfl_xor(v, 16); v += __shfl_xor(v, 32);
                if (q == 0) qpart[w][rt * 16 + m] = v;
            }
        }
    }
    __syncthreads();                                       // (4)

    if (wantq && tid < RB) {
        float qs = b3[0];
        #pragma unroll
        for (int ww = 0; ww < 8; ++ww) qs += qpart[ww][tid];
        qout[row0 + tid] = qs;
    }

    // ---- Phase D: dh1 = dz2 @ w2^T ; dz1 = dh1 * mask -> AF
    #pragma unroll
    for (int tc = 0; tc < 2; ++tc)
        #pragma unroll
        for (int rt = 0; rt < 4; ++rt) acc[rt][tc] = (f32x4){0.f, 0.f, 0.f, 0.f};
    for (int c = 0; c < 8; ++c) {
        bf16x8 af[4];
        #pragma unroll
        for (int rt = 0; rt < 4; ++rt)
            af[rt] = *(const bf16x8*)&AF[((rt * 8 + c) * 64 + lane) * 8];
        #pragma unroll
        for (int tc = 0; tc < 2; ++tc) {
            bf16x8 wfr = *(const bf16x8*)&pB3[(((w * 2 + tc) * 8 + c) * 64 + lane) * 8];
            #pragma unroll
            for (int rt = 0; rt < 4; ++rt)
                acc[rt][tc] = __builtin_amdgcn_mfma_f32_16x16x32_bf16(wfr, af[rt], acc[rt][tc], 0, 0, 0);
        }
    }
    __syncthreads();                                       // (5)
    #pragma unroll
    for (int tc = 0; tc < 2; ++tc) {
        const int tile = w * 2 + tc;
        const int kblk = tile >> 1;
        const int koff = ((tile & 1) << 4) + q * 4;
        const int qp_  = koff >> 3, j0 = koff & 7;
        #pragma unroll
        for (int rt = 0; rt < 4; ++rt) {
            ushort4 pk;
            pk.x = f2bf((relumask >> (rt * 8 + tc * 4 + 0)) & 1u ? acc[rt][tc][0] : 0.f);
            pk.y = f2bf((relumask >> (rt * 8 + tc * 4 + 1)) & 1u ? acc[rt][tc][1] : 0.f);
            pk.z = f2bf((relumask >> (rt * 8 + tc * 4 + 2)) & 1u ? acc[rt][tc][2] : 0.f);
            pk.w = f2bf((relumask >> (rt * 8 + tc * 4 + 3)) & 1u ? acc[rt][tc][3] : 0.f);
            *(ushort4*)&AF[(((rt * 8 + kblk) * 64 + qp_ * 16 + m) << 3) + j0] = pk;
        }
    }
    __syncthreads();                                       // (6)

    // ---- Phase E: score = dz1 @ w1[64:80]^T (waves 0..3, row-tile w)
    if (w < 4) {
        f32x4 acc2 = (f32x4){0.f, 0.f, 0.f, 0.f};
        for (int c = 0; c < 8; ++c) {
            bf16x8 af = *(const bf16x8*)&AF[((w * 8 + c) * 64 + lane) * 8];
            bf16x8 wfr = *(const bf16x8*)&pB4[(c * 64 + lane) * 8];
            acc2 = __builtin_amdgcn_mfma_f32_16x16x32_bf16(wfr, af, acc2, 0, 0, 0);
        }
        float4 o; o.x = acc2[0]; o.y = acc2[1]; o.z = acc2[2]; o.w = acc2[3];
        *(float4*)&score[(size_t)(row0 + w * 16 + m) * 16 + q * 4] = o;
    }
}

// ---------------------------------------------------------------------------
// SVGD v6 (round-6, proven): wave-per-state, zero __syncthreads, register-only
// binary-search median (bit-exact). Unchanged.
__global__ __launch_bounds__(256, 2) void svgd6(
    const float* __restrict__ a_in,    // [BN,16]
    const float* __restrict__ score,   // [BN,16]
    const float* __restrict__ logp_in, // [BN] (ignored if first)
    float* __restrict__ logp_out,      // [BN]
    float* __restrict__ a_out,         // [BN,16]
    int first)
{
    __shared__ __align__(16) float X4[4][32 * 20];
    __shared__ __align__(16) float S4[4][32 * 20];
    __shared__ __align__(16) float KM4[4][1024];

    const int tid    = threadIdx.x;
    const int wv     = tid >> 6;
    const int lane   = tid & 63;
    const int stateg = blockIdx.x * 4 + wv;
    const size_t base = (size_t)stateg * 512;      // floats

    float* X  = X4[wv];
    float* S  = S4[wv];
    float* KM = KM4[wv];

    // ---- stage own state's a/score (wave-local; 8 floats per lane per array)
    {
        int g0 = lane * 8;
        int r = g0 >> 4, d0 = g0 & 15;             // d0 in {0,8}
        float4 va0 = *(const float4*)&a_in[base + g0];
        float4 va1 = *(const float4*)&a_in[base + g0 + 4];
        float4 vs0 = *(const float4*)&score[base + g0];
        float4 vs1 = *(const float4*)&score[base + g0 + 4];
        *(float4*)&X[r * 20 + d0]     = va0;
        *(float4*)&X[r * 20 + d0 + 4] = va1;
        *(float4*)&S[r * 20 + d0]     = vs0;
        *(float4*)&S[r * 20 + d0 + 4] = vs1;
    }
    __asm__ volatile("s_waitcnt lgkmcnt(0)" ::: "memory");

    const int half = lane >> 5;
    const int j    = lane & 31;

    // ---- cache own column (rows X[j], S[j]) in registers
    float Xj[16], Sj[16];
    #pragma unroll
    for (int d0 = 0; d0 < 16; d0 += 4) {
        float4 xv = *(const float4*)&X[j * 20 + d0];
        float4 sv = *(const float4*)&S[j * 20 + d0];
        Xj[d0 + 0] = xv.x; Xj[d0 + 1] = xv.y; Xj[d0 + 2] = xv.z; Xj[d0 + 3] = xv.w;
        Sj[d0 + 0] = sv.x; Sj[d0 + 1] = sv.y; Sj[d0 + 2] = sv.z; Sj[d0 + 3] = sv.w;
    }

    // ---- dist^2 (as uint bits) + P for 16 pairs (i = half*16+t, j)
    unsigned v[16]; float p[16];
    #pragma unroll 4
    for (int t = 0; t < 16; ++t) {
        const float* Xi = &X[(half * 16 + t) * 20];
        float ss = 0.f, pp = 0.f;
        #pragma unroll
        for (int d0 = 0; d0 < 16; d0 += 4) {
            float4 xv = *(const float4*)&Xi[d0];
            float df0 = xv.x - Xj[d0 + 0];
            float df1 = xv.y - Xj[d0 + 1];
            float df2 = xv.z - Xj[d0 + 2];
            float df3 = xv.w - Xj[d0 + 3];
            ss = fmaf(df0, df0, ss); pp = fmaf(df0, Sj[d0 + 0], pp);
            ss = fmaf(df1, df1, ss); pp = fmaf(df1, Sj[d0 + 1], pp);
            ss = fmaf(df2, df2, ss); pp = fmaf(df2, Sj[d0 + 2], pp);
            ss = fmaf(df3, df3, ss); pp = fmaf(df3, Sj[d0 + 3], pp);
        }
        v[t] = __float_as_uint(ss);
        p[t] = pp;
    }

    // ---- median via register-only rank select (bit-exact vs radix)
    unsigned vmin, vmax;
    {
        unsigned mn = 0xFFFFFFFFu, mx = 0u;
        #pragma unroll
        for (int t = 0; t < 16; ++t) {
            mn = min(mn, v[t]); mx = max(mx, v[t]);
        }
        #pragma unroll
        for (int off = 1; off < 64; off <<= 1) {
            mn = min(mn, (unsigned)__shfl_xor((int)mn, off));
            mx = max(mx, (unsigned)__shfl_xor((int)mx, off));
        }
        vmin = mn; vmax = mx;
    }
    unsigned lo = vmin, hi = vmax;
    while (lo < hi) {                       // uniform across the wave
        unsigned mid = lo + ((hi - lo) >> 1);
        int c = 0;
        #pragma unroll
        for (int t = 0; t < 16; ++t) c += (v[t] <= mid) ? 1 : 0;
        #pragma unroll
        for (int off = 1; off < 64; off <<= 1) c += __shfl_xor(c, off);
        if (c >= 512) hi = mid; else lo = mid + 1;
    }
    const unsigned prefix = lo;             // bits of sorted[511]
    const float v1 = __uint_as_float(prefix);

    // ---- rank-512: v1 if count(x<=v1)>=513 else min of x>v1 (wave reduce)
    int cle = 0;
    unsigned mgt = 0xFFFFFFFFu;
    #pragma unroll
    for (int t = 0; t < 16; ++t) {
        if (v[t] <= prefix) cle++;
        else mgt = min(mgt, v[t]);
    }
    #pragma unroll
    for (int off = 1; off < 64; off <<= 1) {
        cle += __shfl_xor(cle, off);
        mgt = min(mgt, (unsigned)__shfl_xor((int)mgt, off));
    }
    const float v2  = (cle >= 513) ? v1 : __uint_as_float(mgt);
    const float med = 0.5f * (v1 + v2);
    const float gamma = 1.0f / (2.0f * (med / LN32 + 1e-8f));

    // ---- K -> swizzled KM ; logp row-reduce fused in
    #pragma unroll 4
    for (int t = 0; t < 16; ++t) {
        int i = half * 16 + t;
        float kk = __expf(-gamma * __uint_as_float(v[t]));
        KM[i * 32 + (j ^ i)] = kk;
        float acc = fmaf(fmaf(2.f * gamma, __uint_as_float(v[t]), -16.f), kk,
                         kk * p[t]);
        #pragma unroll
        for (int off = 1; off < 32; off <<= 1)
            acc += __shfl_xor(acc, off);
        if (j == 0) {
            float tmp = -2.f * gamma * acc * (1.f / 32.f);
            float prev = first ? 0.f : logp_in[stateg * 32 + i];
            logp_out[stateg * 32 + i] = prev - 0.1f * tmp;
        }
    }
    __asm__ volatile("s_waitcnt lgkmcnt(0)" ::: "memory");

    // ---- phi + particle update: lane owns 8 (i,d) entries, d = lane&15
    {
        const int d  = lane & 15;
        const int i0 = lane >> 4;              // entry e -> row i0 + 4e
        float s1[8], s2[8], xi[8];
        #pragma unroll
        for (int e = 0; e < 8; ++e) {
            s1[e] = 0.f; s2[e] = 0.f;
            xi[e] = X[(i0 + 4 * e) * 20 + d];
        }
        for (int jj = 0; jj < 32; ++jj) {
            float xjv = X[jj * 20 + d];
            float sjv = S[jj * 20 + d];
            #pragma unroll
            for (int e = 0; e < 8; ++e) {
                int i = i0 + 4 * e;
                float kk = KM[i * 32 + (jj ^ i)];
                s1[e] = fmaf(kk, sjv, s1[e]);
                s2[e] = fmaf(kk, xi[e] - xjv, s2[e]);
            }
        }
        #pragma unroll
        for (int e = 0; e < 8; ++e) {
            int i = i0 + 4 * e;
            float phi = (s1[e] + 2.f * gamma * s2[e]) * (1.f / 32.f);
            float av = xi[e] + 0.1f * phi;
            av = fminf(fmaxf(av, -1.f), 1.f);
            a_out[base + i * 16 + d] = av;
        }
    }
}

// ---------------------------------------------------------------------------
extern "C" void kernel_launch(void* const* d_in, const int* in_sizes, int n_in,
                              void* d_out, int out_size, void* d_ws, size_t ws_size,
                              hipStream_t stream) {
    const float* obs = (const float*)d_in[0];
    const float* a0  = (const float*)d_in[1];
    const float* w1  = (const float*)d_in[2];
    const float* b1  = (const float*)d_in[3];
    const float* w2  = (const float*)d_in[4];
    const float* b2  = (const float*)d_in[5];
    const float* w3  = (const float*)d_in[6];
    const float* b3  = (const float*)d_in[7];

    float* out_a    = (float*)d_out;                 // [BN,16]
    float* out_logp = out_a + (size_t)BNROWS * 16;   // [BN]
    float* out_q    = out_logp + BNROWS;             // [BN]

    char* p = (char*)d_ws;
    ushort* pB1 = (ushort*)p; p += 24576 * 2;
    ushort* pB2 = (ushort*)p; p += 65536 * 2;
    ushort* pB3 = (ushort*)p; p += 65536 * 2;
    ushort* pB4 = (ushort*)p; p += 4096 * 2;
    ushort* obs_bf = (ushort*)p; p += (size_t)BNROWS * 64 * 2;
    float* abuf0 = (float*)p; p += (size_t)BNROWS * 16 * 4;
    float* abuf1 = (float*)p; p += (size_t)BNROWS * 16 * 4;
    float* scr   = (float*)p; p += (size_t)BNROWS * 16 * 4;
    float* logp  = (float*)p; p += (size_t)BNROWS * 4;
    float* qtmp  = (float*)p;

    prep_all<<<8270, 256, 0, stream>>>(obs, obs_bf, w1, w2, pB1, pB2, pB3, pB4);

    const int MB = BNROWS / RB;   // 2048 blocks
    const int SB = 4096 / 4;      // 1024 blocks, 4 states (waves) each

    // step 1
    mlp_mfma<<<MB, 512, 0, stream>>>(obs_bf, a0, b1, b2, w3, b3,
                                     pB1, pB2, pB3, pB4, scr, qtmp, 0);
    svgd6<<<SB, 256, 0, stream>>>(a0, scr, nullptr, logp, abuf0, 1);
    // step 2
    mlp_mfma<<<MB, 512, 0, stream>>>(obs_bf, abuf0, b1, b2, w3, b3,
                                     pB1, pB2, pB3, pB4, scr, qtmp, 0);
    svgd6<<<SB, 256, 0, stream>>>(abuf0, scr, logp, logp, abuf1, 0);
    // step 3 (q of this step is the q_vals output)
    mlp_mfma<<<MB, 512, 0, stream>>>(obs_bf, abuf1, b1, b2, w3, b3,
                                     pB1, pB2, pB3, pB4, scr, out_q, 1);
    svgd6<<<SB, 256, 0, stream>>>(abuf1, scr, logp, out_logp, out_a, 0);
}

// Round 8
// 340.357 us; speedup vs baseline: 1.0885x; 1.0885x over previous
//
#include <hip/hip_runtime.h>
#include <hip/hip_bf16.h>
#include <math.h>

#define BNROWS (4096*32)   // 131072
#define RB     64          // rows per MLP block
#define LN32   3.4657359027997265f

typedef __attribute__((ext_vector_type(8))) short bf16x8;
typedef __attribute__((ext_vector_type(4))) float f32x4;

static __device__ __forceinline__ ushort f2bf(float x) {
    union { __hip_bfloat16 h; ushort u; } cv;
    cv.h = __float2bfloat16(x);
    return cv.u;
}

// ---------------------------------------------------------------------------
// Merged prep: blocks [0,8192) convert obs f32->bf16; blocks [8192,8270) pack
// weights into MFMA fragment order. Saves one launch vs separate kernels.
__global__ void prep_all(const float* __restrict__ obs,
                         ushort* __restrict__ obs_bf,
                         const float* __restrict__ w1,
                         const float* __restrict__ w2,
                         ushort* __restrict__ pB1, ushort* __restrict__ pB2,
                         ushort* __restrict__ pB3, ushort* __restrict__ pB4) {
    if (blockIdx.x < 8192) {
        size_t i = ((size_t)blockIdx.x * 256 + threadIdx.x) * 4;
        float4 v = *(const float4*)&obs[i];
        ushort4 o;
        o.x = f2bf(v.x); o.y = f2bf(v.y); o.z = f2bf(v.z); o.w = f2bf(v.w);
        *(ushort4*)&obs_bf[i] = o;
        return;
    }
    int g = (blockIdx.x - 8192) * 256 + threadIdx.x;   // 19968 total
    ushort out[8];
    ushort* dst;
    if (g < 3072) {
        int lane = g & 63, gc = g >> 6;
        int t = gc / 3, c = gc % 3;
        int m = lane & 15, q = lane >> 4, n = t * 16 + m;
        #pragma unroll
        for (int j = 0; j < 8; ++j) {
            int k = c * 32 + q * 8 + j;
            out[j] = f2bf((k < 80) ? w1[k * 256 + n] : 0.f);
        }
        dst = &pB1[g * 8];
    } else if (g < 11264) {
        int gg = g - 3072;
        int lane = gg & 63, gc = gg >> 6;
        int t = gc >> 3, c = gc & 7;
        int m = lane & 15, q = lane >> 4, n = t * 16 + m;
        #pragma unroll
        for (int j = 0; j < 8; ++j)
            out[j] = f2bf(w2[(c * 32 + q * 8 + j) * 256 + n]);
        dst = &pB2[gg * 8];
    } else if (g < 19456) {
        int gg = g - 11264;
        int lane = gg & 63, gc = gg >> 6;
        int t = gc >> 3, c = gc & 7;
        int m = lane & 15, q = lane >> 4;
        #pragma unroll
        for (int j = 0; j < 8; ++j)
            out[j] = f2bf(w2[(t * 16 + m) * 256 + c * 32 + q * 8 + j]);
        dst = &pB3[gg * 8];
    } else if (g < 19968) {
        int gg = g - 19456;
        int lane = gg & 63, c = gg >> 6;
        int m = lane & 15, q = lane >> 4;
        #pragma unroll
        for (int j = 0; j < 8; ++j)
            out[j] = f2bf(w1[(64 + m) * 256 + c * 32 + q * 8 + j]);
        dst = &pB4[gg * 8];
    } else return;
    *(uint4*)dst = *(uint4*)out;
}

// ---------------------------------------------------------------------------
// Fused critic forward + VJP, bf16 MFMA — round-0 structure + wantq flag.
// (Round-7 lesson: fragment-order LDS + global obs staging regressed 56.5->69;
// bank conflicts were ~1.6% of wave cycles, and global obs latency landed on
// the phase-B critical path. Keep LDS staging exactly as proven.)
__global__ __launch_bounds__(512) void mlp_mfma(
    const ushort* __restrict__ obs_bf,  // [BN,64] bf16
    const float* __restrict__ a_in,     // [BN,16]
    const float* __restrict__ b1,       // [256]
    const float* __restrict__ b2,       // [256]
    const float* __restrict__ w3,       // [256]
    const float* __restrict__ b3,       // [1]
    const ushort* __restrict__ pB1, const ushort* __restrict__ pB2,
    const ushort* __restrict__ pB3, const ushort* __restrict__ pB4,
    float* __restrict__ score,          // [BN,16]
    float* __restrict__ qout,           // [BN]
    int wantq)
{
    __shared__ __align__(16) ushort B0[RB * 264];   // h1 -> dz2 -> dz1
    __shared__ __align__(16) ushort B1s[RB * 104];  // h0
    __shared__ float qpart[8][RB];
    __shared__ float bias1[256], bias2[256], w3s[256];

    const int tid  = threadIdx.x;
    const int row0 = blockIdx.x * RB;

    // ---- Phase A: stage h0 = [obs_bf16 | a->bf16 | 0pad] at stride 104
    {
        int r = tid >> 3, ch = tid & 7;                    // 512 units exactly
        *(uint4*)&B1s[r * 104 + ch * 8] =
            *(const uint4*)&obs_bf[(size_t)(row0 + r) * 64 + ch * 8];
    }
    if (tid < 256) {
        int r = tid >> 2, d0 = (tid & 3) * 4;
        float4 av = *(const float4*)&a_in[(size_t)(row0 + r) * 16 + d0];
        ushort4 pv;
        pv.x = f2bf(av.x); pv.y = f2bf(av.y); pv.z = f2bf(av.z); pv.w = f2bf(av.w);
        *(ushort4*)&B1s[r * 104 + 64 + d0] = pv;
        ushort4 zv; zv.x = zv.y = zv.z = zv.w = 0;
        *(ushort4*)&B1s[r * 104 + 80 + d0] = zv;
        bias1[tid] = b1[tid]; bias2[tid] = b2[tid]; w3s[tid] = w3[tid];
    }
    __syncthreads();                                       // (1)

    const int lane = tid & 63;
    const int w    = tid >> 6;        // wave 0..7 -> col-tiles {2w, 2w+1}
    const int m    = lane & 15;
    const int q    = lane >> 4;
    const int qk   = q * 8;

    f32x4 acc[4][2];                  // [row-tile][col-tile-in-wave]
    unsigned relumask = 0u;           // 32 bits: rt*8 + tc*4 + i

    // ---- Phase B: z1 = h0 @ w1 (+b1) ; relu -> B0 ; mask -> regs
    #pragma unroll
    for (int tc = 0; tc < 2; ++tc)
        #pragma unroll
        for (int rt = 0; rt < 4; ++rt) acc[rt][tc] = (f32x4){0.f, 0.f, 0.f, 0.f};
    for (int c = 0; c < 3; ++c) {
        bf16x8 af[4];
        #pragma unroll
        for (int rt = 0; rt < 4; ++rt)
            af[rt] = *(const bf16x8*)&B1s[(rt * 16 + m) * 104 + c * 32 + qk];
        #pragma unroll
        for (int tc = 0; tc < 2; ++tc) {
            bf16x8 wfr = *(const bf16x8*)&pB1[(((w * 2 + tc) * 3 + c) * 64 + lane) * 8];
            #pragma unroll
            for (int rt = 0; rt < 4; ++rt)
                acc[rt][tc] = __builtin_amdgcn_mfma_f32_16x16x32_bf16(wfr, af[rt], acc[rt][tc], 0, 0, 0);
        }
    }
    #pragma unroll
    for (int tc = 0; tc < 2; ++tc) {
        const float4 bv = *(const float4*)&bias1[(w * 2 + tc) * 16 + q * 4];
        const float bva[4] = {bv.x, bv.y, bv.z, bv.w};
        #pragma unroll
        for (int rt = 0; rt < 4; ++rt) {
            ushort4 pk;
            float z0 = acc[rt][tc][0] + bva[0];
            float z1 = acc[rt][tc][1] + bva[1];
            float z2 = acc[rt][tc][2] + bva[2];
            float z3 = acc[rt][tc][3] + bva[3];
            if (z0 > 0.f) relumask |= 1u << (rt * 8 + tc * 4 + 0);
            if (z1 > 0.f) relumask |= 1u << (rt * 8 + tc * 4 + 1);
            if (z2 > 0.f) relumask |= 1u << (rt * 8 + tc * 4 + 2);
            if (z3 > 0.f) relumask |= 1u << (rt * 8 + tc * 4 + 3);
            pk.x = f2bf(fmaxf(z0, 0.f)); pk.y = f2bf(fmaxf(z1, 0.f));
            pk.z = f2bf(fmaxf(z2, 0.f)); pk.w = f2bf(fmaxf(z3, 0.f));
            *(ushort4*)&B0[(rt * 16 + m) * 264 + (w * 2 + tc) * 16 + q * 4] = pk;
        }
    }
    __syncthreads();                                       // (2)

    // ---- Phase C: z2 = h1 @ w2 (+b2) ; q partials (wantq) ; dz2 -> B0
    #pragma unroll
    for (int tc = 0; tc < 2; ++tc)
        #pragma unroll
        for (int rt = 0; rt < 4; ++rt) acc[rt][tc] = (f32x4){0.f, 0.f, 0.f, 0.f};
    for (int c = 0; c < 8; ++c) {
        bf16x8 af[4];
        #pragma unroll
        for (int rt = 0; rt < 4; ++rt)
            af[rt] = *(const bf16x8*)&B0[(rt * 16 + m) * 264 + c * 32 + qk];
        #pragma unroll
        for (int tc = 0; tc < 2; ++tc) {
            bf16x8 wfr = *(const bf16x8*)&pB2[(((w * 2 + tc) * 8 + c) * 64 + lane) * 8];
            #pragma unroll
            for (int rt = 0; rt < 4; ++rt)
                acc[rt][tc] = __builtin_amdgcn_mfma_f32_16x16x32_bf16(wfr, af[rt], acc[rt][tc], 0, 0, 0);
        }
    }
    __syncthreads();                                       // (3)
    {
        float qp[4] = {0.f, 0.f, 0.f, 0.f};
        #pragma unroll
        for (int tc = 0; tc < 2; ++tc) {
            const float4 bv = *(const float4*)&bias2[(w * 2 + tc) * 16 + q * 4];
            const float4 wv = *(const float4*)&w3s[(w * 2 + tc) * 16 + q * 4];
            const float bva[4] = {bv.x, bv.y, bv.z, bv.w};
            const float wva[4] = {wv.x, wv.y, wv.z, wv.w};
            #pragma unroll
            for (int rt = 0; rt < 4; ++rt) {
                ushort4 pk; float dz[4];
                #pragma unroll
                for (int i = 0; i < 4; ++i) {
                    float z = acc[rt][tc][i] + bva[i];
                    if (z > 0.f) { qp[rt] += z * wva[i]; dz[i] = wva[i]; }
                    else         { dz[i] = 0.f; }
                }
                pk.x = f2bf(dz[0]); pk.y = f2bf(dz[1]);
                pk.z = f2bf(dz[2]); pk.w = f2bf(dz[3]);
                *(ushort4*)&B0[(rt * 16 + m) * 264 + (w * 2 + tc) * 16 + q * 4] = pk;
            }
        }
        if (wantq) {
            #pragma unroll
            for (int rt = 0; rt < 4; ++rt) {
                float v = qp[rt];
                v += __shfl_xor(v, 16); v += __shfl_xor(v, 32);
                if (q == 0) qpart[w][rt * 16 + m] = v;
            }
        }
    }
    __syncthreads();                                       // (4)

    if (wantq && tid < RB) {
        float qs = b3[0];
        #pragma unroll
        for (int ww = 0; ww < 8; ++ww) qs += qpart[ww][tid];
        qout[row0 + tid] = qs;
    }

    // ---- Phase D: dh1 = dz2 @ w2^T ; dz1 = dh1 * mask -> B0
    #pragma unroll
    for (int tc = 0; tc < 2; ++tc)
        #pragma unroll
        for (int rt = 0; rt < 4; ++rt) acc[rt][tc] = (f32x4){0.f, 0.f, 0.f, 0.f};
    for (int c = 0; c < 8; ++c) {
        bf16x8 af[4];
        #pragma unroll
        for (int rt = 0; rt < 4; ++rt)
            af[rt] = *(const bf16x8*)&B0[(rt * 16 + m) * 264 + c * 32 + qk];
        #pragma unroll
        for (int tc = 0; tc < 2; ++tc) {
            bf16x8 wfr = *(const bf16x8*)&pB3[(((w * 2 + tc) * 8 + c) * 64 + lane) * 8];
            #pragma unroll
            for (int rt = 0; rt < 4; ++rt)
                acc[rt][tc] = __builtin_amdgcn_mfma_f32_16x16x32_bf16(wfr, af[rt], acc[rt][tc], 0, 0, 0);
        }
    }
    __syncthreads();                                       // (5)
    #pragma unroll
    for (int rt = 0; rt < 4; ++rt)
        #pragma unroll
        for (int tc = 0; tc < 2; ++tc) {
            ushort4 pk;
            pk.x = f2bf((relumask >> (rt * 8 + tc * 4 + 0)) & 1u ? acc[rt][tc][0] : 0.f);
            pk.y = f2bf((relumask >> (rt * 8 + tc * 4 + 1)) & 1u ? acc[rt][tc][1] : 0.f);
            pk.z = f2bf((relumask >> (rt * 8 + tc * 4 + 2)) & 1u ? acc[rt][tc][2] : 0.f);
            pk.w = f2bf((relumask >> (rt * 8 + tc * 4 + 3)) & 1u ? acc[rt][tc][3] : 0.f);
            *(ushort4*)&B0[(rt * 16 + m) * 264 + (w * 2 + tc) * 16 + q * 4] = pk;
        }
    __syncthreads();                                       // (6)

    // ---- Phase E: score = dz1 @ w1[64:80]^T (waves 0..3, row-tile w)
    if (w < 4) {
        f32x4 acc2 = (f32x4){0.f, 0.f, 0.f, 0.f};
        for (int c = 0; c < 8; ++c) {
            bf16x8 af = *(const bf16x8*)&B0[(w * 16 + m) * 264 + c * 32 + qk];
            bf16x8 wfr = *(const bf16x8*)&pB4[(c * 64 + lane) * 8];
            acc2 = __builtin_amdgcn_mfma_f32_16x16x32_bf16(wfr, af, acc2, 0, 0, 0);
        }
        float4 o; o.x = acc2[0]; o.y = acc2[1]; o.z = acc2[2]; o.w = acc2[3];
        *(float4*)&score[(size_t)(row0 + w * 16 + m) * 16 + q * 4] = o;
    }
}

// ---------------------------------------------------------------------------
// SVGD v6.1: round-6 structure (wave-per-state, zero __syncthreads, register-
// only rank select) with the binary search upgraded to 4-ARY (2 bits/iter):
// three pivots per iteration, counts packed base-1025 into ONE int (per-lane
// partials <=16, field max 1024 < 1025 -> carry-free; total <= 1.08e9 < 2^31)
// so a single 6-shfl reduce serves all three pivots. ~32 -> ~16 dependent
// iterations; the shfl chain is the un-hideable serial cost at 4 waves/SIMD.
// Invariant count(<=hi) >= 512 holds throughout -> result is the exact bit
// pattern of sorted[511]; med/gamma bit-identical to v6.
__global__ __launch_bounds__(256, 2) void svgd6(
    const float* __restrict__ a_in,    // [BN,16]
    const float* __restrict__ score,   // [BN,16]
    const float* __restrict__ logp_in, // [BN] (ignored if first)
    float* __restrict__ logp_out,      // [BN]
    float* __restrict__ a_out,         // [BN,16]
    int first)
{
    __shared__ __align__(16) float X4[4][32 * 20];
    __shared__ __align__(16) float S4[4][32 * 20];
    __shared__ __align__(16) float KM4[4][1024];

    const int tid    = threadIdx.x;
    const int wv     = tid >> 6;
    const int lane   = tid & 63;
    const int stateg = blockIdx.x * 4 + wv;
    const size_t base = (size_t)stateg * 512;      // floats

    float* X  = X4[wv];
    float* S  = S4[wv];
    float* KM = KM4[wv];

    // ---- stage own state's a/score (wave-local; 8 floats per lane per array)
    {
        int g0 = lane * 8;
        int r = g0 >> 4, d0 = g0 & 15;             // d0 in {0,8}
        float4 va0 = *(const float4*)&a_in[base + g0];
        float4 va1 = *(const float4*)&a_in[base + g0 + 4];
        float4 vs0 = *(const float4*)&score[base + g0];
        float4 vs1 = *(const float4*)&score[base + g0 + 4];
        *(float4*)&X[r * 20 + d0]     = va0;
        *(float4*)&X[r * 20 + d0 + 4] = va1;
        *(float4*)&S[r * 20 + d0]     = vs0;
        *(float4*)&S[r * 20 + d0 + 4] = vs1;
    }
    __asm__ volatile("s_waitcnt lgkmcnt(0)" ::: "memory");

    const int half = lane >> 5;
    const int j    = lane & 31;

    // ---- cache own column (rows X[j], S[j]) in registers
    float Xj[16], Sj[16];
    #pragma unroll
    for (int d0 = 0; d0 < 16; d0 += 4) {
        float4 xv = *(const float4*)&X[j * 20 + d0];
        float4 sv = *(const float4*)&S[j * 20 + d0];
        Xj[d0 + 0] = xv.x; Xj[d0 + 1] = xv.y; Xj[d0 + 2] = xv.z; Xj[d0 + 3] = xv.w;
        Sj[d0 + 0] = sv.x; Sj[d0 + 1] = sv.y; Sj[d0 + 2] = sv.z; Sj[d0 + 3] = sv.w;
    }

    // ---- dist^2 (as uint bits) + P for 16 pairs (i = half*16+t, j)
    unsigned v[16]; float p[16];
    #pragma unroll 4
    for (int t = 0; t < 16; ++t) {
        const float* Xi = &X[(half * 16 + t) * 20];
        float ss = 0.f, pp = 0.f;
        #pragma unroll
        for (int d0 = 0; d0 < 16; d0 += 4) {
            float4 xv = *(const float4*)&Xi[d0];
            float df0 = xv.x - Xj[d0 + 0];
            float df1 = xv.y - Xj[d0 + 1];
            float df2 = xv.z - Xj[d0 + 2];
            float df3 = xv.w - Xj[d0 + 3];
            ss = fmaf(df0, df0, ss); pp = fmaf(df0, Sj[d0 + 0], pp);
            ss = fmaf(df1, df1, ss); pp = fmaf(df1, Sj[d0 + 1], pp);
            ss = fmaf(df2, df2, ss); pp = fmaf(df2, Sj[d0 + 2], pp);
            ss = fmaf(df3, df3, ss); pp = fmaf(df3, Sj[d0 + 3], pp);
        }
        v[t] = __float_as_uint(ss);
        p[t] = pp;
    }

    // ---- median via 4-ary register-only rank select (bit-exact)
    unsigned vmin, vmax;
    {
        unsigned mn = 0xFFFFFFFFu, mx = 0u;
        #pragma unroll
        for (int t = 0; t < 16; ++t) {
            mn = min(mn, v[t]); mx = max(mx, v[t]);
        }
        #pragma unroll
        for (int off = 1; off < 64; off <<= 1) {
            mn = min(mn, (unsigned)__shfl_xor((int)mn, off));
            mx = max(mx, (unsigned)__shfl_xor((int)mx, off));
        }
        vmin = mn; vmax = mx;
    }
    unsigned lo = vmin, hi = vmax;
    while (lo < hi) {                       // uniform across the wave
        const unsigned span = hi - lo;
        const unsigned m1 = lo + (span >> 2);
        const unsigned m2 = lo + (span >> 1);
        const unsigned m3 = lo + span - (span >> 2);
        int P = 0;
        #pragma unroll
        for (int t = 0; t < 16; ++t) {
            P += (v[t] <= m1) ? 1 : 0;
            P += (v[t] <= m2) ? 1025 : 0;
            P += (v[t] <= m3) ? 1050625 : 0;
        }
        #pragma unroll
        for (int off = 1; off < 64; off <<= 1) P += __shfl_xor(P, off);
        const int c1 = P % 1025;
        const int c2 = (P / 1025) % 1025;
        const int c3 = P / 1050625;
        if (c1 >= 512)      { hi = m1; }
        else if (c2 >= 512) { lo = m1 + 1; hi = m2; }
        else if (c3 >= 512) { lo = m2 + 1; hi = m3; }
        else                { lo = m3 + 1; }
    }
    const unsigned prefix = lo;             // bits of sorted[511]
    const float v1 = __uint_as_float(prefix);

    // ---- rank-512: v1 if count(x<=v1)>=513 else min of x>v1 (wave reduce)
    int cle = 0;
    unsigned mgt = 0xFFFFFFFFu;
    #pragma unroll
    for (int t = 0; t < 16; ++t) {
        if (v[t] <= prefix) cle++;
        else mgt = min(mgt, v[t]);
    }
    #pragma unroll
    for (int off = 1; off < 64; off <<= 1) {
        cle += __shfl_xor(cle, off);
        mgt = min(mgt, (unsigned)__shfl_xor((int)mgt, off));
    }
    const float v2  = (cle >= 513) ? v1 : __uint_as_float(mgt);
    const float med = 0.5f * (v1 + v2);
    const float gamma = 1.0f / (2.0f * (med / LN32 + 1e-8f));

    // ---- K -> swizzled KM ; logp row-reduce fused in
    #pragma unroll 4
    for (int t = 0; t < 16; ++t) {
        int i = half * 16 + t;
        float kk = __expf(-gamma * __uint_as_float(v[t]));
        KM[i * 32 + (j ^ i)] = kk;
        float acc = fmaf(fmaf(2.f * gamma, __uint_as_float(v[t]), -16.f), kk,
                         kk * p[t]);
        #pragma unroll
        for (int off = 1; off < 32; off <<= 1)
            acc += __shfl_xor(acc, off);
        if (j == 0) {
            float tmp = -2.f * gamma * acc * (1.f / 32.f);
            float prev = first ? 0.f : logp_in[stateg * 32 + i];
            logp_out[stateg * 32 + i] = prev - 0.1f * tmp;
        }
    }
    __asm__ volatile("s_waitcnt lgkmcnt(0)" ::: "memory");

    // ---- phi + particle update: lane owns 8 (i,d) entries, d = lane&15
    {
        const int d  = lane & 15;
        const int i0 = lane >> 4;              // entry e -> row i0 + 4e
        float s1[8], s2[8], xi[8];
        #pragma unroll
        for (int e = 0; e < 8; ++e) {
            s1[e] = 0.f; s2[e] = 0.f;
            xi[e] = X[(i0 + 4 * e) * 20 + d];
        }
        for (int jj = 0; jj < 32; ++jj) {
            float xjv = X[jj * 20 + d];
            float sjv = S[jj * 20 + d];
            #pragma unroll
            for (int e = 0; e < 8; ++e) {
                int i = i0 + 4 * e;
                float kk = KM[i * 32 + (jj ^ i)];
                s1[e] = fmaf(kk, sjv, s1[e]);
                s2[e] = fmaf(kk, xi[e] - xjv, s2[e]);
            }
        }
        #pragma unroll
        for (int e = 0; e < 8; ++e) {
            int i = i0 + 4 * e;
            float phi = (s1[e] + 2.f * gamma * s2[e]) * (1.f / 32.f);
            float av = xi[e] + 0.1f * phi;
            av = fminf(fmaxf(av, -1.f), 1.f);
            a_out[base + i * 16 + d] = av;
        }
    }
}

// ---------------------------------------------------------------------------
extern "C" void kernel_launch(void* const* d_in, const int* in_sizes, int n_in,
                              void* d_out, int out_size, void* d_ws, size_t ws_size,
                              hipStream_t stream) {
    const float* obs = (const float*)d_in[0];
    const float* a0  = (const float*)d_in[1];
    const float* w1  = (const float*)d_in[2];
    const float* b1  = (const float*)d_in[3];
    const float* w2  = (const float*)d_in[4];
    const float* b2  = (const float*)d_in[5];
    const float* w3  = (const float*)d_in[6];
    const float* b3  = (const float*)d_in[7];

    float* out_a    = (float*)d_out;                 // [BN,16]
    float* out_logp = out_a + (size_t)BNROWS * 16;   // [BN]
    float* out_q    = out_logp + BNROWS;             // [BN]

    char* p = (char*)d_ws;
    ushort* pB1 = (ushort*)p; p += 24576 * 2;
    ushort* pB2 = (ushort*)p; p += 65536 * 2;
    ushort* pB3 = (ushort*)p; p += 65536 * 2;
    ushort* pB4 = (ushort*)p; p += 4096 * 2;
    ushort* obs_bf = (ushort*)p; p += (size_t)BNROWS * 64 * 2;
    float* abuf0 = (float*)p; p += (size_t)BNROWS * 16 * 4;
    float* abuf1 = (float*)p; p += (size_t)BNROWS * 16 * 4;
    float* scr   = (float*)p; p += (size_t)BNROWS * 16 * 4;
    float* logp  = (float*)p; p += (size_t)BNROWS * 4;
    float* qtmp  = (float*)p;

    prep_all<<<8270, 256, 0, stream>>>(obs, obs_bf, w1, w2, pB1, pB2, pB3, pB4);

    const int MB = BNROWS / RB;   // 2048 blocks
    const int SB = 4096 / 4;      // 1024 blocks, 4 states (waves) each

    // step 1
    mlp_mfma<<<MB, 512, 0, stream>>>(obs_bf, a0, b1, b2, w3, b3,
                                     pB1, pB2, pB3, pB4, scr, qtmp, 0);
    svgd6<<<SB, 256, 0, stream>>>(a0, scr, nullptr, logp, abuf0, 1);
    // step 2
    mlp_mfma<<<MB, 512, 0, stream>>>(obs_bf, abuf0, b1, b2, w3, b3,
                                     pB1, pB2, pB3, pB4, scr, qtmp, 0);
    svgd6<<<SB, 256, 0, stream>>>(abuf0, scr, logp, logp, abuf1, 0);
    // step 3 (q of this step is the q_vals output)
    mlp_mfma<<<MB, 512, 0, stream>>>(obs_bf, abuf1, b1, b2, w3, b3,
                                     pB1, pB2, pB3, pB4, scr, out_q, 1);
    svgd6<<<SB, 256, 0, stream>>>(abuf1, scr, logp, out_logp, out_a, 0);
}

// Round 9
// 334.955 us; speedup vs baseline: 1.1060x; 1.0161x over previous
//
#include <hip/hip_runtime.h>
#include <hip/hip_bf16.h>
#include <math.h>

#define BNROWS (4096*32)   // 131072
#define RB     64          // rows per MLP block
#define LN32   3.4657359027997265f

typedef __attribute__((ext_vector_type(8))) short bf16x8;
typedef __attribute__((ext_vector_type(4))) float f32x4;

static __device__ __forceinline__ ushort f2bf(float x) {
    union { __hip_bfloat16 h; ushort u; } cv;
    cv.h = __float2bfloat16(x);
    return cv.u;
}

// ---------------------------------------------------------------------------
// Merged prep: blocks [0,8192) convert obs f32->bf16; blocks [8192,8270) pack
// weights into MFMA fragment order. Saves one launch vs separate kernels.
__global__ void prep_all(const float* __restrict__ obs,
                         ushort* __restrict__ obs_bf,
                         const float* __restrict__ w1,
                         const float* __restrict__ w2,
                         ushort* __restrict__ pB1, ushort* __restrict__ pB2,
                         ushort* __restrict__ pB3, ushort* __restrict__ pB4) {
    if (blockIdx.x < 8192) {
        size_t i = ((size_t)blockIdx.x * 256 + threadIdx.x) * 4;
        float4 v = *(const float4*)&obs[i];
        ushort4 o;
        o.x = f2bf(v.x); o.y = f2bf(v.y); o.z = f2bf(v.z); o.w = f2bf(v.w);
        *(ushort4*)&obs_bf[i] = o;
        return;
    }
    int g = (blockIdx.x - 8192) * 256 + threadIdx.x;   // 19968 total
    ushort out[8];
    ushort* dst;
    if (g < 3072) {
        int lane = g & 63, gc = g >> 6;
        int t = gc / 3, c = gc % 3;
        int m = lane & 15, q = lane >> 4, n = t * 16 + m;
        #pragma unroll
        for (int j = 0; j < 8; ++j) {
            int k = c * 32 + q * 8 + j;
            out[j] = f2bf((k < 80) ? w1[k * 256 + n] : 0.f);
        }
        dst = &pB1[g * 8];
    } else if (g < 11264) {
        int gg = g - 3072;
        int lane = gg & 63, gc = gg >> 6;
        int t = gc >> 3, c = gc & 7;
        int m = lane & 15, q = lane >> 4, n = t * 16 + m;
        #pragma unroll
        for (int j = 0; j < 8; ++j)
            out[j] = f2bf(w2[(c * 32 + q * 8 + j) * 256 + n]);
        dst = &pB2[gg * 8];
    } else if (g < 19456) {
        int gg = g - 11264;
        int lane = gg & 63, gc = gg >> 6;
        int t = gc >> 3, c = gc & 7;
        int m = lane & 15, q = lane >> 4;
        #pragma unroll
        for (int j = 0; j < 8; ++j)
            out[j] = f2bf(w2[(t * 16 + m) * 256 + c * 32 + q * 8 + j]);
        dst = &pB3[gg * 8];
    } else if (g < 19968) {
        int gg = g - 19456;
        int lane = gg & 63, c = gg >> 6;
        int m = lane & 15, q = lane >> 4;
        #pragma unroll
        for (int j = 0; j < 8; ++j)
            out[j] = f2bf(w1[(64 + m) * 256 + c * 32 + q * 8 + j]);
        dst = &pB4[gg * 8];
    } else return;
    *(uint4*)dst = *(uint4*)out;
}

// ---------------------------------------------------------------------------
// Fused critic forward + VJP, bf16 MFMA — round-0 structure + wantq flag.
// (Round-7 lesson: fragment-order LDS + global obs staging regressed 56.5->69;
// bank conflicts were ~1.6% of wave cycles. Keep LDS staging exactly as is.)
__global__ __launch_bounds__(512) void mlp_mfma(
    const ushort* __restrict__ obs_bf,  // [BN,64] bf16
    const float* __restrict__ a_in,     // [BN,16]
    const float* __restrict__ b1,       // [256]
    const float* __restrict__ b2,       // [256]
    const float* __restrict__ w3,       // [256]
    const float* __restrict__ b3,       // [1]
    const ushort* __restrict__ pB1, const ushort* __restrict__ pB2,
    const ushort* __restrict__ pB3, const ushort* __restrict__ pB4,
    float* __restrict__ score,          // [BN,16]
    float* __restrict__ qout,           // [BN]
    int wantq)
{
    __shared__ __align__(16) ushort B0[RB * 264];   // h1 -> dz2 -> dz1
    __shared__ __align__(16) ushort B1s[RB * 104];  // h0
    __shared__ float qpart[8][RB];
    __shared__ float bias1[256], bias2[256], w3s[256];

    const int tid  = threadIdx.x;
    const int row0 = blockIdx.x * RB;

    // ---- Phase A: stage h0 = [obs_bf16 | a->bf16 | 0pad] at stride 104
    {
        int r = tid >> 3, ch = tid & 7;                    // 512 units exactly
        *(uint4*)&B1s[r * 104 + ch * 8] =
            *(const uint4*)&obs_bf[(size_t)(row0 + r) * 64 + ch * 8];
    }
    if (tid < 256) {
        int r = tid >> 2, d0 = (tid & 3) * 4;
        float4 av = *(const float4*)&a_in[(size_t)(row0 + r) * 16 + d0];
        ushort4 pv;
        pv.x = f2bf(av.x); pv.y = f2bf(av.y); pv.z = f2bf(av.z); pv.w = f2bf(av.w);
        *(ushort4*)&B1s[r * 104 + 64 + d0] = pv;
        ushort4 zv; zv.x = zv.y = zv.z = zv.w = 0;
        *(ushort4*)&B1s[r * 104 + 80 + d0] = zv;
        bias1[tid] = b1[tid]; bias2[tid] = b2[tid]; w3s[tid] = w3[tid];
    }
    __syncthreads();                                       // (1)

    const int lane = tid & 63;
    const int w    = tid >> 6;        // wave 0..7 -> col-tiles {2w, 2w+1}
    const int m    = lane & 15;
    const int q    = lane >> 4;
    const int qk   = q * 8;

    f32x4 acc[4][2];                  // [row-tile][col-tile-in-wave]
    unsigned relumask = 0u;           // 32 bits: rt*8 + tc*4 + i

    // ---- Phase B: z1 = h0 @ w1 (+b1) ; relu -> B0 ; mask -> regs
    #pragma unroll
    for (int tc = 0; tc < 2; ++tc)
        #pragma unroll
        for (int rt = 0; rt < 4; ++rt) acc[rt][tc] = (f32x4){0.f, 0.f, 0.f, 0.f};
    for (int c = 0; c < 3; ++c) {
        bf16x8 af[4];
        #pragma unroll
        for (int rt = 0; rt < 4; ++rt)
            af[rt] = *(const bf16x8*)&B1s[(rt * 16 + m) * 104 + c * 32 + qk];
        #pragma unroll
        for (int tc = 0; tc < 2; ++tc) {
            bf16x8 wfr = *(const bf16x8*)&pB1[(((w * 2 + tc) * 3 + c) * 64 + lane) * 8];
            #pragma unroll
            for (int rt = 0; rt < 4; ++rt)
                acc[rt][tc] = __builtin_amdgcn_mfma_f32_16x16x32_bf16(wfr, af[rt], acc[rt][tc], 0, 0, 0);
        }
    }
    #pragma unroll
    for (int tc = 0; tc < 2; ++tc) {
        const float4 bv = *(const float4*)&bias1[(w * 2 + tc) * 16 + q * 4];
        const float bva[4] = {bv.x, bv.y, bv.z, bv.w};
        #pragma unroll
        for (int rt = 0; rt < 4; ++rt) {
            ushort4 pk;
            float z0 = acc[rt][tc][0] + bva[0];
            float z1 = acc[rt][tc][1] + bva[1];
            float z2 = acc[rt][tc][2] + bva[2];
            float z3 = acc[rt][tc][3] + bva[3];
            if (z0 > 0.f) relumask |= 1u << (rt * 8 + tc * 4 + 0);
            if (z1 > 0.f) relumask |= 1u << (rt * 8 + tc * 4 + 1);
            if (z2 > 0.f) relumask |= 1u << (rt * 8 + tc * 4 + 2);
            if (z3 > 0.f) relumask |= 1u << (rt * 8 + tc * 4 + 3);
            pk.x = f2bf(fmaxf(z0, 0.f)); pk.y = f2bf(fmaxf(z1, 0.f));
            pk.z = f2bf(fmaxf(z2, 0.f)); pk.w = f2bf(fmaxf(z3, 0.f));
            *(ushort4*)&B0[(rt * 16 + m) * 264 + (w * 2 + tc) * 16 + q * 4] = pk;
        }
    }
    __syncthreads();                                       // (2)

    // ---- Phase C: z2 = h1 @ w2 (+b2) ; q partials (wantq) ; dz2 -> B0
    #pragma unroll
    for (int tc = 0; tc < 2; ++tc)
        #pragma unroll
        for (int rt = 0; rt < 4; ++rt) acc[rt][tc] = (f32x4){0.f, 0.f, 0.f, 0.f};
    for (int c = 0; c < 8; ++c) {
        bf16x8 af[4];
        #pragma unroll
        for (int rt = 0; rt < 4; ++rt)
            af[rt] = *(const bf16x8*)&B0[(rt * 16 + m) * 264 + c * 32 + qk];
        #pragma unroll
        for (int tc = 0; tc < 2; ++tc) {
            bf16x8 wfr = *(const bf16x8*)&pB2[(((w * 2 + tc) * 8 + c) * 64 + lane) * 8];
            #pragma unroll
            for (int rt = 0; rt < 4; ++rt)
                acc[rt][tc] = __builtin_amdgcn_mfma_f32_16x16x32_bf16(wfr, af[rt], acc[rt][tc], 0, 0, 0);
        }
    }
    __syncthreads();                                       // (3)
    {
        float qp[4] = {0.f, 0.f, 0.f, 0.f};
        #pragma unroll
        for (int tc = 0; tc < 2; ++tc) {
            const float4 bv = *(const float4*)&bias2[(w * 2 + tc) * 16 + q * 4];
            const float4 wv = *(const float4*)&w3s[(w * 2 + tc) * 16 + q * 4];
            const float bva[4] = {bv.x, bv.y, bv.z, bv.w};
            const float wva[4] = {wv.x, wv.y, wv.z, wv.w};
            #pragma unroll
            for (int rt = 0; rt < 4; ++rt) {
                ushort4 pk; float dz[4];
                #pragma unroll
                for (int i = 0; i < 4; ++i) {
                    float z = acc[rt][tc][i] + bva[i];
                    if (z > 0.f) { qp[rt] += z * wva[i]; dz[i] = wva[i]; }
                    else         { dz[i] = 0.f; }
                }
                pk.x = f2bf(dz[0]); pk.y = f2bf(dz[1]);
                pk.z = f2bf(dz[2]); pk.w = f2bf(dz[3]);
                *(ushort4*)&B0[(rt * 16 + m) * 264 + (w * 2 + tc) * 16 + q * 4] = pk;
            }
        }
        if (wantq) {
            #pragma unroll
            for (int rt = 0; rt < 4; ++rt) {
                float v = qp[rt];
                v += __shfl_xor(v, 16); v += __shfl_xor(v, 32);
                if (q == 0) qpart[w][rt * 16 + m] = v;
            }
        }
    }
    __syncthreads();                                       // (4)

    if (wantq && tid < RB) {
        float qs = b3[0];
        #pragma unroll
        for (int ww = 0; ww < 8; ++ww) qs += qpart[ww][tid];
        qout[row0 + tid] = qs;
    }

    // ---- Phase D: dh1 = dz2 @ w2^T ; dz1 = dh1 * mask -> B0
    #pragma unroll
    for (int tc = 0; tc < 2; ++tc)
        #pragma unroll
        for (int rt = 0; rt < 4; ++rt) acc[rt][tc] = (f32x4){0.f, 0.f, 0.f, 0.f};
    for (int c = 0; c < 8; ++c) {
        bf16x8 af[4];
        #pragma unroll
        for (int rt = 0; rt < 4; ++rt)
            af[rt] = *(const bf16x8*)&B0[(rt * 16 + m) * 264 + c * 32 + qk];
        #pragma unroll
        for (int tc = 0; tc < 2; ++tc) {
            bf16x8 wfr = *(const bf16x8*)&pB3[(((w * 2 + tc) * 8 + c) * 64 + lane) * 8];
            #pragma unroll
            for (int rt = 0; rt < 4; ++rt)
                acc[rt][tc] = __builtin_amdgcn_mfma_f32_16x16x32_bf16(wfr, af[rt], acc[rt][tc], 0, 0, 0);
        }
    }
    __syncthreads();                                       // (5)
    #pragma unroll
    for (int rt = 0; rt < 4; ++rt)
        #pragma unroll
        for (int tc = 0; tc < 2; ++tc) {
            ushort4 pk;
            pk.x = f2bf((relumask >> (rt * 8 + tc * 4 + 0)) & 1u ? acc[rt][tc][0] : 0.f);
            pk.y = f2bf((relumask >> (rt * 8 + tc * 4 + 1)) & 1u ? acc[rt][tc][1] : 0.f);
            pk.z = f2bf((relumask >> (rt * 8 + tc * 4 + 2)) & 1u ? acc[rt][tc][2] : 0.f);
            pk.w = f2bf((relumask >> (rt * 8 + tc * 4 + 3)) & 1u ? acc[rt][tc][3] : 0.f);
            *(ushort4*)&B0[(rt * 16 + m) * 264 + (w * 2 + tc) * 16 + q * 4] = pk;
        }
    __syncthreads();                                       // (6)

    // ---- Phase E: score = dz1 @ w1[64:80]^T (waves 0..3, row-tile w)
    if (w < 4) {
        f32x4 acc2 = (f32x4){0.f, 0.f, 0.f, 0.f};
        for (int c = 0; c < 8; ++c) {
            bf16x8 af = *(const bf16x8*)&B0[(w * 16 + m) * 264 + c * 32 + qk];
            bf16x8 wfr = *(const bf16x8*)&pB4[(c * 64 + lane) * 8];
            acc2 = __builtin_amdgcn_mfma_f32_16x16x32_bf16(wfr, af, acc2, 0, 0, 0);
        }
        float4 o; o.x = acc2[0]; o.y = acc2[1]; o.z = acc2[2]; o.w = acc2[3];
        *(float4*)&score[(size_t)(row0 + w * 16 + m) * 16 + q * 4] = o;
    }
}

// ---------------------------------------------------------------------------
// SVGD v6.2: round-6 structure (wave-per-state, zero __syncthreads, binary-
// search median — proven; round-8's 4-ary reverted: tripled per-iter VALU
// while keeping the same shfl-chain latency). ROUND-9 change: phi ownership
// remapped to one ROW per lane-pair (i = lane>>1, d-half = (lane&1)*8):
//  - per j-iter LDS ops drop 10 -> 5 (1 broadcast KM read + 2x float4 X +
//    2x float4 S, all from the same row j -> pure broadcast);
//  - KM banks: (j^i)&31 distinct across the 32 rows, pairs broadcast;
//  - a_out store becomes 2 coalesced float4 per lane (2 KB/wave).
// Accumulation order over j unchanged -> bit-identical output.
__global__ __launch_bounds__(256, 2) void svgd6(
    const float* __restrict__ a_in,    // [BN,16]
    const float* __restrict__ score,   // [BN,16]
    const float* __restrict__ logp_in, // [BN] (ignored if first)
    float* __restrict__ logp_out,      // [BN]
    float* __restrict__ a_out,         // [BN,16]
    int first)
{
    __shared__ __align__(16) float X4[4][32 * 20];
    __shared__ __align__(16) float S4[4][32 * 20];
    __shared__ __align__(16) float KM4[4][1024];

    const int tid    = threadIdx.x;
    const int wv     = tid >> 6;
    const int lane   = tid & 63;
    const int stateg = blockIdx.x * 4 + wv;
    const size_t base = (size_t)stateg * 512;      // floats

    float* X  = X4[wv];
    float* S  = S4[wv];
    float* KM = KM4[wv];

    // ---- stage own state's a/score (wave-local; 8 floats per lane per array)
    {
        int g0 = lane * 8;
        int r = g0 >> 4, d0 = g0 & 15;             // d0 in {0,8}
        float4 va0 = *(const float4*)&a_in[base + g0];
        float4 va1 = *(const float4*)&a_in[base + g0 + 4];
        float4 vs0 = *(const float4*)&score[base + g0];
        float4 vs1 = *(const float4*)&score[base + g0 + 4];
        *(float4*)&X[r * 20 + d0]     = va0;
        *(float4*)&X[r * 20 + d0 + 4] = va1;
        *(float4*)&S[r * 20 + d0]     = vs0;
        *(float4*)&S[r * 20 + d0 + 4] = vs1;
    }
    __asm__ volatile("s_waitcnt lgkmcnt(0)" ::: "memory");

    const int half = lane >> 5;
    const int j    = lane & 31;

    // ---- cache own column (rows X[j], S[j]) in registers
    float Xj[16], Sj[16];
    #pragma unroll
    for (int d0 = 0; d0 < 16; d0 += 4) {
        float4 xv = *(const float4*)&X[j * 20 + d0];
        float4 sv = *(const float4*)&S[j * 20 + d0];
        Xj[d0 + 0] = xv.x; Xj[d0 + 1] = xv.y; Xj[d0 + 2] = xv.z; Xj[d0 + 3] = xv.w;
        Sj[d0 + 0] = sv.x; Sj[d0 + 1] = sv.y; Sj[d0 + 2] = sv.z; Sj[d0 + 3] = sv.w;
    }

    // ---- dist^2 (as uint bits) + P for 16 pairs (i = half*16+t, j)
    unsigned v[16]; float p[16];
    #pragma unroll 4
    for (int t = 0; t < 16; ++t) {
        const float* Xi = &X[(half * 16 + t) * 20];
        float ss = 0.f, pp = 0.f;
        #pragma unroll
        for (int d0 = 0; d0 < 16; d0 += 4) {
            float4 xv = *(const float4*)&Xi[d0];
            float df0 = xv.x - Xj[d0 + 0];
            float df1 = xv.y - Xj[d0 + 1];
            float df2 = xv.z - Xj[d0 + 2];
            float df3 = xv.w - Xj[d0 + 3];
            ss = fmaf(df0, df0, ss); pp = fmaf(df0, Sj[d0 + 0], pp);
            ss = fmaf(df1, df1, ss); pp = fmaf(df1, Sj[d0 + 1], pp);
            ss = fmaf(df2, df2, ss); pp = fmaf(df2, Sj[d0 + 2], pp);
            ss = fmaf(df3, df3, ss); pp = fmaf(df3, Sj[d0 + 3], pp);
        }
        v[t] = __float_as_uint(ss);
        p[t] = pp;
    }

    // ---- median via register-only binary rank select (bit-exact)
    unsigned vmin, vmax;
    {
        unsigned mn = 0xFFFFFFFFu, mx = 0u;
        #pragma unroll
        for (int t = 0; t < 16; ++t) {
            mn = min(mn, v[t]); mx = max(mx, v[t]);
        }
        #pragma unroll
        for (int off = 1; off < 64; off <<= 1) {
            mn = min(mn, (unsigned)__shfl_xor((int)mn, off));
            mx = max(mx, (unsigned)__shfl_xor((int)mx, off));
        }
        vmin = mn; vmax = mx;
    }
    unsigned lo = vmin, hi = vmax;
    while (lo < hi) {                       // uniform across the wave
        unsigned mid = lo + ((hi - lo) >> 1);
        int c = 0;
        #pragma unroll
        for (int t = 0; t < 16; ++t) c += (v[t] <= mid) ? 1 : 0;
        #pragma unroll
        for (int off = 1; off < 64; off <<= 1) c += __shfl_xor(c, off);
        if (c >= 512) hi = mid; else lo = mid + 1;
    }
    const unsigned prefix = lo;             // bits of sorted[511]
    const float v1 = __uint_as_float(prefix);

    // ---- rank-512: v1 if count(x<=v1)>=513 else min of x>v1 (wave reduce)
    int cle = 0;
    unsigned mgt = 0xFFFFFFFFu;
    #pragma unroll
    for (int t = 0; t < 16; ++t) {
        if (v[t] <= prefix) cle++;
        else mgt = min(mgt, v[t]);
    }
    #pragma unroll
    for (int off = 1; off < 64; off <<= 1) {
        cle += __shfl_xor(cle, off);
        mgt = min(mgt, (unsigned)__shfl_xor((int)mgt, off));
    }
    const float v2  = (cle >= 513) ? v1 : __uint_as_float(mgt);
    const float med = 0.5f * (v1 + v2);
    const float gamma = 1.0f / (2.0f * (med / LN32 + 1e-8f));

    // ---- K -> swizzled KM ; logp row-reduce fused in
    #pragma unroll 4
    for (int t = 0; t < 16; ++t) {
        int i = half * 16 + t;
        float kk = __expf(-gamma * __uint_as_float(v[t]));
        KM[i * 32 + (j ^ i)] = kk;
        float acc = fmaf(fmaf(2.f * gamma, __uint_as_float(v[t]), -16.f), kk,
                         kk * p[t]);
        #pragma unroll
        for (int off = 1; off < 32; off <<= 1)
            acc += __shfl_xor(acc, off);
        if (j == 0) {
            float tmp = -2.f * gamma * acc * (1.f / 32.f);
            float prev = first ? 0.f : logp_in[stateg * 32 + i];
            logp_out[stateg * 32 + i] = prev - 0.1f * tmp;
        }
    }
    __asm__ volatile("s_waitcnt lgkmcnt(0)" ::: "memory");

    // ---- phi + particle update: lane-pair owns one row (i = lane>>1),
    //      this lane covers d = dh..dh+7 where dh = (lane&1)*8.
    {
        const int i  = lane >> 1;
        const int dh = (lane & 1) * 8;
        float s1[8], s2[8], xi[8];
        {
            float4 xa = *(const float4*)&X[i * 20 + dh];
            float4 xb = *(const float4*)&X[i * 20 + dh + 4];
            xi[0] = xa.x; xi[1] = xa.y; xi[2] = xa.z; xi[3] = xa.w;
            xi[4] = xb.x; xi[5] = xb.y; xi[6] = xb.z; xi[7] = xb.w;
        }
        #pragma unroll
        for (int e = 0; e < 8; ++e) { s1[e] = 0.f; s2[e] = 0.f; }
        for (int jj = 0; jj < 32; ++jj) {
            float kk = KM[i * 32 + (jj ^ i)];
            float4 xj0 = *(const float4*)&X[jj * 20 + dh];
            float4 xj1 = *(const float4*)&X[jj * 20 + dh + 4];
            float4 sj0 = *(const float4*)&S[jj * 20 + dh];
            float4 sj1 = *(const float4*)&S[jj * 20 + dh + 4];
            s1[0] = fmaf(kk, sj0.x, s1[0]); s2[0] = fmaf(kk, xi[0] - xj0.x, s2[0]);
            s1[1] = fmaf(kk, sj0.y, s1[1]); s2[1] = fmaf(kk, xi[1] - xj0.y, s2[1]);
            s1[2] = fmaf(kk, sj0.z, s1[2]); s2[2] = fmaf(kk, xi[2] - xj0.z, s2[2]);
            s1[3] = fmaf(kk, sj0.w, s1[3]); s2[3] = fmaf(kk, xi[3] - xj0.w, s2[3]);
            s1[4] = fmaf(kk, sj1.x, s1[4]); s2[4] = fmaf(kk, xi[4] - xj1.x, s2[4]);
            s1[5] = fmaf(kk, sj1.y, s1[5]); s2[5] = fmaf(kk, xi[5] - xj1.y, s2[5]);
            s1[6] = fmaf(kk, sj1.z, s1[6]); s2[6] = fmaf(kk, xi[6] - xj1.z, s2[6]);
            s1[7] = fmaf(kk, sj1.w, s1[7]); s2[7] = fmaf(kk, xi[7] - xj1.w, s2[7]);
        }
        float o[8];
        #pragma unroll
        for (int e = 0; e < 8; ++e) {
            float phi = (s1[e] + 2.f * gamma * s2[e]) * (1.f / 32.f);
            float av = xi[e] + 0.1f * phi;
            o[e] = fminf(fmaxf(av, -1.f), 1.f);
        }
        float4 o0; o0.x = o[0]; o0.y = o[1]; o0.z = o[2]; o0.w = o[3];
        float4 o1; o1.x = o[4]; o1.y = o[5]; o1.z = o[6]; o1.w = o[7];
        *(float4*)&a_out[base + i * 16 + dh]     = o0;
        *(float4*)&a_out[base + i * 16 + dh + 4] = o1;
    }
}

// ---------------------------------------------------------------------------
extern "C" void kernel_launch(void* const* d_in, const int* in_sizes, int n_in,
                              void* d_out, int out_size, void* d_ws, size_t ws_size,
                              hipStream_t stream) {
    const float* obs = (const float*)d_in[0];
    const float* a0  = (const float*)d_in[1];
    const float* w1  = (const float*)d_in[2];
    const float* b1  = (const float*)d_in[3];
    const float* w2  = (const float*)d_in[4];
    const float* b2  = (const float*)d_in[5];
    const float* w3  = (const float*)d_in[6];
    const float* b3  = (const float*)d_in[7];

    float* out_a    = (float*)d_out;                 // [BN,16]
    float* out_logp = out_a + (size_t)BNROWS * 16;   // [BN]
    float* out_q    = out_logp + BNROWS;             // [BN]

    char* p = (char*)d_ws;
    ushort* pB1 = (ushort*)p; p += 24576 * 2;
    ushort* pB2 = (ushort*)p; p += 65536 * 2;
    ushort* pB3 = (ushort*)p; p += 65536 * 2;
    ushort* pB4 = (ushort*)p; p += 4096 * 2;
    ushort* obs_bf = (ushort*)p; p += (size_t)BNROWS * 64 * 2;
    float* abuf0 = (float*)p; p += (size_t)BNROWS * 16 * 4;
    float* abuf1 = (float*)p; p += (size_t)BNROWS * 16 * 4;
    float* scr   = (float*)p; p += (size_t)BNROWS * 16 * 4;
    float* logp  = (float*)p; p += (size_t)BNROWS * 4;
    float* qtmp  = (float*)p;

    prep_all<<<8270, 256, 0, stream>>>(obs, obs_bf, w1, w2, pB1, pB2, pB3, pB4);

    const int MB = BNROWS / RB;   // 2048 blocks
    const int SB = 4096 / 4;      // 1024 blocks, 4 states (waves) each

    // step 1
    mlp_mfma<<<MB, 512, 0, stream>>>(obs_bf, a0, b1, b2, w3, b3,
                                     pB1, pB2, pB3, pB4, scr, qtmp, 0);
    svgd6<<<SB, 256, 0, stream>>>(a0, scr, nullptr, logp, abuf0, 1);
    // step 2
    mlp_mfma<<<MB, 512, 0, stream>>>(obs_bf, abuf0, b1, b2, w3, b3,
                                     pB1, pB2, pB3, pB4, scr, qtmp, 0);
    svgd6<<<SB, 256, 0, stream>>>(abuf0, scr, logp, logp, abuf1, 0);
    // step 3 (q of this step is the q_vals output)
    mlp_mfma<<<MB, 512, 0, stream>>>(obs_bf, abuf1, b1, b2, w3, b3,
                                     pB1, pB2, pB3, pB4, scr, out_q, 1);
    svgd6<<<SB, 256, 0, stream>>>(abuf1, scr, logp, out_logp, out_a, 0);
}

// Round 10
// 322.477 us; speedup vs baseline: 1.1488x; 1.0387x over previous
//
#include <hip/hip_runtime.h>
#include <hip/hip_bf16.h>
#include <math.h>

#define BNROWS (4096*32)   // 131072
#define RB     64          // rows per MLP block
#define LN32   3.4657359027997265f

typedef __attribute__((ext_vector_type(8))) short bf16x8;
typedef __attribute__((ext_vector_type(4))) float f32x4;

static __device__ __forceinline__ ushort f2bf(float x) {
    union { __hip_bfloat16 h; ushort u; } cv;
    cv.h = __float2bfloat16(x);
    return cv.u;
}

// ---------------------------------------------------------------------------
// Weight pack only (obs conversion moved into mlp phase A — round 10).
// Pack weights into MFMA fragment order (lane-contiguous 16B loads).
__global__ void prep_pack(const float* __restrict__ w1,
                          const float* __restrict__ w2,
                          ushort* __restrict__ pB1, ushort* __restrict__ pB2,
                          ushort* __restrict__ pB3, ushort* __restrict__ pB4) {
    int g = blockIdx.x * 256 + threadIdx.x;   // 19968 total
    ushort out[8];
    ushort* dst;
    if (g < 3072) {
        int lane = g & 63, gc = g >> 6;
        int t = gc / 3, c = gc % 3;
        int m = lane & 15, q = lane >> 4, n = t * 16 + m;
        #pragma unroll
        for (int j = 0; j < 8; ++j) {
            int k = c * 32 + q * 8 + j;
            out[j] = f2bf((k < 80) ? w1[k * 256 + n] : 0.f);
        }
        dst = &pB1[g * 8];
    } else if (g < 11264) {
        int gg = g - 3072;
        int lane = gg & 63, gc = gg >> 6;
        int t = gc >> 3, c = gc & 7;
        int m = lane & 15, q = lane >> 4, n = t * 16 + m;
        #pragma unroll
        for (int j = 0; j < 8; ++j)
            out[j] = f2bf(w2[(c * 32 + q * 8 + j) * 256 + n]);
        dst = &pB2[gg * 8];
    } else if (g < 19456) {
        int gg = g - 11264;
        int lane = gg & 63, gc = gg >> 6;
        int t = gc >> 3, c = gc & 7;
        int m = lane & 15, q = lane >> 4;
        #pragma unroll
        for (int j = 0; j < 8; ++j)
            out[j] = f2bf(w2[(t * 16 + m) * 256 + c * 32 + q * 8 + j]);
        dst = &pB3[gg * 8];
    } else if (g < 19968) {
        int gg = g - 19456;
        int lane = gg & 63, c = gg >> 6;
        int m = lane & 15, q = lane >> 4;
        #pragma unroll
        for (int j = 0; j < 8; ++j)
            out[j] = f2bf(w1[(64 + m) * 256 + c * 32 + q * 8 + j]);
        dst = &pB4[gg * 8];
    } else return;
    *(uint4*)dst = *(uint4*)out;
}

// ---------------------------------------------------------------------------
// Fused critic forward + VJP, bf16 MFMA — round-6 structure (proven 56.5 us).
// ROUND-10: phase A stages obs straight from f32 global (32 B/thread + 8
// f2bf), deleting the 8192-block obs->bf16 prep pass. HBM totals neutral
// (3x32 MB vs 32+16+3x16 MB); later dispatches hit L3. All else identical.
__global__ __launch_bounds__(512) void mlp_mfma(
    const float* __restrict__ obs,      // [BN,64] f32
    const float* __restrict__ a_in,     // [BN,16]
    const float* __restrict__ b1,       // [256]
    const float* __restrict__ b2,       // [256]
    const float* __restrict__ w3,       // [256]
    const float* __restrict__ b3,       // [1]
    const ushort* __restrict__ pB1, const ushort* __restrict__ pB2,
    const ushort* __restrict__ pB3, const ushort* __restrict__ pB4,
    float* __restrict__ score,          // [BN,16]
    float* __restrict__ qout,           // [BN]
    int wantq)
{
    __shared__ __align__(16) ushort B0[RB * 264];   // h1 -> dz2 -> dz1
    __shared__ __align__(16) ushort B1s[RB * 104];  // h0
    __shared__ float qpart[8][RB];
    __shared__ float bias1[256], bias2[256], w3s[256];

    const int tid  = threadIdx.x;
    const int row0 = blockIdx.x * RB;

    // ---- Phase A: stage h0 = [obs(f32->bf16) | a->bf16 | 0pad] at stride 104
    {
        int r = tid >> 3, ch = tid & 7;                    // 512 units exactly
        const float* op = &obs[(size_t)(row0 + r) * 64 + ch * 8];
        float4 v0 = *(const float4*)op;
        float4 v1 = *(const float4*)(op + 4);
        ushort o[8];
        o[0] = f2bf(v0.x); o[1] = f2bf(v0.y); o[2] = f2bf(v0.z); o[3] = f2bf(v0.w);
        o[4] = f2bf(v1.x); o[5] = f2bf(v1.y); o[6] = f2bf(v1.z); o[7] = f2bf(v1.w);
        *(uint4*)&B1s[r * 104 + ch * 8] = *(uint4*)o;
    }
    if (tid < 256) {
        int r = tid >> 2, d0 = (tid & 3) * 4;
        float4 av = *(const float4*)&a_in[(size_t)(row0 + r) * 16 + d0];
        ushort4 pv;
        pv.x = f2bf(av.x); pv.y = f2bf(av.y); pv.z = f2bf(av.z); pv.w = f2bf(av.w);
        *(ushort4*)&B1s[r * 104 + 64 + d0] = pv;
        ushort4 zv; zv.x = zv.y = zv.z = zv.w = 0;
        *(ushort4*)&B1s[r * 104 + 80 + d0] = zv;
        bias1[tid] = b1[tid]; bias2[tid] = b2[tid]; w3s[tid] = w3[tid];
    }
    __syncthreads();                                       // (1)

    const int lane = tid & 63;
    const int w    = tid >> 6;        // wave 0..7 -> col-tiles {2w, 2w+1}
    const int m    = lane & 15;
    const int q    = lane >> 4;
    const int qk   = q * 8;

    f32x4 acc[4][2];                  // [row-tile][col-tile-in-wave]
    unsigned relumask = 0u;           // 32 bits: rt*8 + tc*4 + i

    // ---- Phase B: z1 = h0 @ w1 (+b1) ; relu -> B0 ; mask -> regs
    #pragma unroll
    for (int tc = 0; tc < 2; ++tc)
        #pragma unroll
        for (int rt = 0; rt < 4; ++rt) acc[rt][tc] = (f32x4){0.f, 0.f, 0.f, 0.f};
    for (int c = 0; c < 3; ++c) {
        bf16x8 af[4];
        #pragma unroll
        for (int rt = 0; rt < 4; ++rt)
            af[rt] = *(const bf16x8*)&B1s[(rt * 16 + m) * 104 + c * 32 + qk];
        #pragma unroll
        for (int tc = 0; tc < 2; ++tc) {
            bf16x8 wfr = *(const bf16x8*)&pB1[(((w * 2 + tc) * 3 + c) * 64 + lane) * 8];
            #pragma unroll
            for (int rt = 0; rt < 4; ++rt)
                acc[rt][tc] = __builtin_amdgcn_mfma_f32_16x16x32_bf16(wfr, af[rt], acc[rt][tc], 0, 0, 0);
        }
    }
    #pragma unroll
    for (int tc = 0; tc < 2; ++tc) {
        const float4 bv = *(const float4*)&bias1[(w * 2 + tc) * 16 + q * 4];
        const float bva[4] = {bv.x, bv.y, bv.z, bv.w};
        #pragma unroll
        for (int rt = 0; rt < 4; ++rt) {
            ushort4 pk;
            float z0 = acc[rt][tc][0] + bva[0];
            float z1 = acc[rt][tc][1] + bva[1];
            float z2 = acc[rt][tc][2] + bva[2];
            float z3 = acc[rt][tc][3] + bva[3];
            if (z0 > 0.f) relumask |= 1u << (rt * 8 + tc * 4 + 0);
            if (z1 > 0.f) relumask |= 1u << (rt * 8 + tc * 4 + 1);
            if (z2 > 0.f) relumask |= 1u << (rt * 8 + tc * 4 + 2);
            if (z3 > 0.f) relumask |= 1u << (rt * 8 + tc * 4 + 3);
            pk.x = f2bf(fmaxf(z0, 0.f)); pk.y = f2bf(fmaxf(z1, 0.f));
            pk.z = f2bf(fmaxf(z2, 0.f)); pk.w = f2bf(fmaxf(z3, 0.f));
            *(ushort4*)&B0[(rt * 16 + m) * 264 + (w * 2 + tc) * 16 + q * 4] = pk;
        }
    }
    __syncthreads();                                       // (2)

    // ---- Phase C: z2 = h1 @ w2 (+b2) ; q partials (wantq) ; dz2 -> B0
    #pragma unroll
    for (int tc = 0; tc < 2; ++tc)
        #pragma unroll
        for (int rt = 0; rt < 4; ++rt) acc[rt][tc] = (f32x4){0.f, 0.f, 0.f, 0.f};
    for (int c = 0; c < 8; ++c) {
        bf16x8 af[4];
        #pragma unroll
        for (int rt = 0; rt < 4; ++rt)
            af[rt] = *(const bf16x8*)&B0[(rt * 16 + m) * 264 + c * 32 + qk];
        #pragma unroll
        for (int tc = 0; tc < 2; ++tc) {
            bf16x8 wfr = *(const bf16x8*)&pB2[(((w * 2 + tc) * 8 + c) * 64 + lane) * 8];
            #pragma unroll
            for (int rt = 0; rt < 4; ++rt)
                acc[rt][tc] = __builtin_amdgcn_mfma_f32_16x16x32_bf16(wfr, af[rt], acc[rt][tc], 0, 0, 0);
        }
    }
    __syncthreads();                                       // (3)
    {
        float qp[4] = {0.f, 0.f, 0.f, 0.f};
        #pragma unroll
        for (int tc = 0; tc < 2; ++tc) {
            const float4 bv = *(const float4*)&bias2[(w * 2 + tc) * 16 + q * 4];
            const float4 wv = *(const float4*)&w3s[(w * 2 + tc) * 16 + q * 4];
            const float bva[4] = {bv.x, bv.y, bv.z, bv.w};
            const float wva[4] = {wv.x, wv.y, wv.z, wv.w};
            #pragma unroll
            for (int rt = 0; rt < 4; ++rt) {
                ushort4 pk; float dz[4];
                #pragma unroll
                for (int i = 0; i < 4; ++i) {
                    float z = acc[rt][tc][i] + bva[i];
                    if (z > 0.f) { qp[rt] += z * wva[i]; dz[i] = wva[i]; }
                    else         { dz[i] = 0.f; }
                }
                pk.x = f2bf(dz[0]); pk.y = f2bf(dz[1]);
                pk.z = f2bf(dz[2]); pk.w = f2bf(dz[3]);
                *(ushort4*)&B0[(rt * 16 + m) * 264 + (w * 2 + tc) * 16 + q * 4] = pk;
            }
        }
        if (wantq) {
            #pragma unroll
            for (int rt = 0; rt < 4; ++rt) {
                float v = qp[rt];
                v += __shfl_xor(v, 16); v += __shfl_xor(v, 32);
                if (q == 0) qpart[w][rt * 16 + m] = v;
            }
        }
    }
    __syncthreads();                                       // (4)

    if (wantq && tid < RB) {
        float qs = b3[0];
        #pragma unroll
        for (int ww = 0; ww < 8; ++ww) qs += qpart[ww][tid];
        qout[row0 + tid] = qs;
    }

    // ---- Phase D: dh1 = dz2 @ w2^T ; dz1 = dh1 * mask -> B0
    #pragma unroll
    for (int tc = 0; tc < 2; ++tc)
        #pragma unroll
        for (int rt = 0; rt < 4; ++rt) acc[rt][tc] = (f32x4){0.f, 0.f, 0.f, 0.f};
    for (int c = 0; c < 8; ++c) {
        bf16x8 af[4];
        #pragma unroll
        for (int rt = 0; rt < 4; ++rt)
            af[rt] = *(const bf16x8*)&B0[(rt * 16 + m) * 264 + c * 32 + qk];
        #pragma unroll
        for (int tc = 0; tc < 2; ++tc) {
            bf16x8 wfr = *(const bf16x8*)&pB3[(((w * 2 + tc) * 8 + c) * 64 + lane) * 8];
            #pragma unroll
            for (int rt = 0; rt < 4; ++rt)
                acc[rt][tc] = __builtin_amdgcn_mfma_f32_16x16x32_bf16(wfr, af[rt], acc[rt][tc], 0, 0, 0);
        }
    }
    __syncthreads();                                       // (5)
    #pragma unroll
    for (int rt = 0; rt < 4; ++rt)
        #pragma unroll
        for (int tc = 0; tc < 2; ++tc) {
            ushort4 pk;
            pk.x = f2bf((relumask >> (rt * 8 + tc * 4 + 0)) & 1u ? acc[rt][tc][0] : 0.f);
            pk.y = f2bf((relumask >> (rt * 8 + tc * 4 + 1)) & 1u ? acc[rt][tc][1] : 0.f);
            pk.z = f2bf((relumask >> (rt * 8 + tc * 4 + 2)) & 1u ? acc[rt][tc][2] : 0.f);
            pk.w = f2bf((relumask >> (rt * 8 + tc * 4 + 3)) & 1u ? acc[rt][tc][3] : 0.f);
            *(ushort4*)&B0[(rt * 16 + m) * 264 + (w * 2 + tc) * 16 + q * 4] = pk;
        }
    __syncthreads();                                       // (6)

    // ---- Phase E: score = dz1 @ w1[64:80]^T (waves 0..3, row-tile w)
    if (w < 4) {
        f32x4 acc2 = (f32x4){0.f, 0.f, 0.f, 0.f};
        for (int c = 0; c < 8; ++c) {
            bf16x8 af = *(const bf16x8*)&B0[(w * 16 + m) * 264 + c * 32 + qk];
            bf16x8 wfr = *(const bf16x8*)&pB4[(c * 64 + lane) * 8];
            acc2 = __builtin_amdgcn_mfma_f32_16x16x32_bf16(wfr, af, acc2, 0, 0, 0);
        }
        float4 o; o.x = acc2[0]; o.y = acc2[1]; o.z = acc2[2]; o.w = acc2[3];
        *(float4*)&score[(size_t)(row0 + w * 16 + m) * 16 + q * 4] = o;
    }
}

// ---------------------------------------------------------------------------
// SVGD v6 (round-6, proven): wave-per-state, zero __syncthreads, register-only
// binary-search median (bit-exact). Round-8 4-ary and round-9 phi-remap both
// reverted (neutral-to-negative). Byte-identical to the 326.8 us config.
__global__ __launch_bounds__(256, 2) void svgd6(
    const float* __restrict__ a_in,    // [BN,16]
    const float* __restrict__ score,   // [BN,16]
    const float* __restrict__ logp_in, // [BN] (ignored if first)
    float* __restrict__ logp_out,      // [BN]
    float* __restrict__ a_out,         // [BN,16]
    int first)
{
    __shared__ __align__(16) float X4[4][32 * 20];
    __shared__ __align__(16) float S4[4][32 * 20];
    __shared__ __align__(16) float KM4[4][1024];

    const int tid    = threadIdx.x;
    const int wv     = tid >> 6;
    const int lane   = tid & 63;
    const int stateg = blockIdx.x * 4 + wv;
    const size_t base = (size_t)stateg * 512;      // floats

    float* X  = X4[wv];
    float* S  = S4[wv];
    float* KM = KM4[wv];

    // ---- stage own state's a/score (wave-local; 8 floats per lane per array)
    {
        int g0 = lane * 8;
        int r = g0 >> 4, d0 = g0 & 15;             // d0 in {0,8}
        float4 va0 = *(const float4*)&a_in[base + g0];
        float4 va1 = *(const float4*)&a_in[base + g0 + 4];
        float4 vs0 = *(const float4*)&score[base + g0];
        float4 vs1 = *(const float4*)&score[base + g0 + 4];
        *(float4*)&X[r * 20 + d0]     = va0;
        *(float4*)&X[r * 20 + d0 + 4] = va1;
        *(float4*)&S[r * 20 + d0]     = vs0;
        *(float4*)&S[r * 20 + d0 + 4] = vs1;
    }
    __asm__ volatile("s_waitcnt lgkmcnt(0)" ::: "memory");

    const int half = lane >> 5;
    const int j    = lane & 31;

    // ---- cache own column (rows X[j], S[j]) in registers
    float Xj[16], Sj[16];
    #pragma unroll
    for (int d0 = 0; d0 < 16; d0 += 4) {
        float4 xv = *(const float4*)&X[j * 20 + d0];
        float4 sv = *(const float4*)&S[j * 20 + d0];
        Xj[d0 + 0] = xv.x; Xj[d0 + 1] = xv.y; Xj[d0 + 2] = xv.z; Xj[d0 + 3] = xv.w;
        Sj[d0 + 0] = sv.x; Sj[d0 + 1] = sv.y; Sj[d0 + 2] = sv.z; Sj[d0 + 3] = sv.w;
    }

    // ---- dist^2 (as uint bits) + P for 16 pairs (i = half*16+t, j)
    unsigned v[16]; float p[16];
    #pragma unroll 4
    for (int t = 0; t < 16; ++t) {
        const float* Xi = &X[(half * 16 + t) * 20];
        float ss = 0.f, pp = 0.f;
        #pragma unroll
        for (int d0 = 0; d0 < 16; d0 += 4) {
            float4 xv = *(const float4*)&Xi[d0];
            float df0 = xv.x - Xj[d0 + 0];
            float df1 = xv.y - Xj[d0 + 1];
            float df2 = xv.z - Xj[d0 + 2];
            float df3 = xv.w - Xj[d0 + 3];
            ss = fmaf(df0, df0, ss); pp = fmaf(df0, Sj[d0 + 0], pp);
            ss = fmaf(df1, df1, ss); pp = fmaf(df1, Sj[d0 + 1], pp);
            ss = fmaf(df2, df2, ss); pp = fmaf(df2, Sj[d0 + 2], pp);
            ss = fmaf(df3, df3, ss); pp = fmaf(df3, Sj[d0 + 3], pp);
        }
        v[t] = __float_as_uint(ss);
        p[t] = pp;
    }

    // ---- median via register-only binary rank select (bit-exact)
    unsigned vmin, vmax;
    {
        unsigned mn = 0xFFFFFFFFu, mx = 0u;
        #pragma unroll
        for (int t = 0; t < 16; ++t) {
            mn = min(mn, v[t]); mx = max(mx, v[t]);
        }
        #pragma unroll
        for (int off = 1; off < 64; off <<= 1) {
            mn = min(mn, (unsigned)__shfl_xor((int)mn, off));
            mx = max(mx, (unsigned)__shfl_xor((int)mx, off));
        }
        vmin = mn; vmax = mx;
    }
    unsigned lo = vmin, hi = vmax;
    while (lo < hi) {                       // uniform across the wave
        unsigned mid = lo + ((hi - lo) >> 1);
        int c = 0;
        #pragma unroll
        for (int t = 0; t < 16; ++t) c += (v[t] <= mid) ? 1 : 0;
        #pragma unroll
        for (int off = 1; off < 64; off <<= 1) c += __shfl_xor(c, off);
        if (c >= 512) hi = mid; else lo = mid + 1;
    }
    const unsigned prefix = lo;             // bits of sorted[511]
    const float v1 = __uint_as_float(prefix);

    // ---- rank-512: v1 if count(x<=v1)>=513 else min of x>v1 (wave reduce)
    int cle = 0;
    unsigned mgt = 0xFFFFFFFFu;
    #pragma unroll
    for (int t = 0; t < 16; ++t) {
        if (v[t] <= prefix) cle++;
        else mgt = min(mgt, v[t]);
    }
    #pragma unroll
    for (int off = 1; off < 64; off <<= 1) {
        cle += __shfl_xor(cle, off);
        mgt = min(mgt, (unsigned)__shfl_xor((int)mgt, off));
    }
    const float v2  = (cle >= 513) ? v1 : __uint_as_float(mgt);
    const float med = 0.5f * (v1 + v2);
    const float gamma = 1.0f / (2.0f * (med / LN32 + 1e-8f));

    // ---- K -> swizzled KM ; logp row-reduce fused in
    #pragma unroll 4
    for (int t = 0; t < 16; ++t) {
        int i = half * 16 + t;
        float kk = __expf(-gamma * __uint_as_float(v[t]));
        KM[i * 32 + (j ^ i)] = kk;
        float acc = fmaf(fmaf(2.f * gamma, __uint_as_float(v[t]), -16.f), kk,
                         kk * p[t]);
        #pragma unroll
        for (int off = 1; off < 32; off <<= 1)
            acc += __shfl_xor(acc, off);
        if (j == 0) {
            float tmp = -2.f * gamma * acc * (1.f / 32.f);
            float prev = first ? 0.f : logp_in[stateg * 32 + i];
            logp_out[stateg * 32 + i] = prev - 0.1f * tmp;
        }
    }
    __asm__ volatile("s_waitcnt lgkmcnt(0)" ::: "memory");

    // ---- phi + particle update: lane owns 8 (i,d) entries, d = lane&15
    {
        const int d  = lane & 15;
        const int i0 = lane >> 4;              // entry e -> row i0 + 4e
        float s1[8], s2[8], xi[8];
        #pragma unroll
        for (int e = 0; e < 8; ++e) {
            s1[e] = 0.f; s2[e] = 0.f;
            xi[e] = X[(i0 + 4 * e) * 20 + d];
        }
        for (int jj = 0; jj < 32; ++jj) {
            float xjv = X[jj * 20 + d];
            float sjv = S[jj * 20 + d];
            #pragma unroll
            for (int e = 0; e < 8; ++e) {
                int i = i0 + 4 * e;
                float kk = KM[i * 32 + (jj ^ i)];
                s1[e] = fmaf(kk, sjv, s1[e]);
                s2[e] = fmaf(kk, xi[e] - xjv, s2[e]);
            }
        }
        #pragma unroll
        for (int e = 0; e < 8; ++e) {
            int i = i0 + 4 * e;
            float phi = (s1[e] + 2.f * gamma * s2[e]) * (1.f / 32.f);
            float av = xi[e] + 0.1f * phi;
            av = fminf(fmaxf(av, -1.f), 1.f);
            a_out[base + i * 16 + d] = av;
        }
    }
}

// ---------------------------------------------------------------------------
extern "C" void kernel_launch(void* const* d_in, const int* in_sizes, int n_in,
                              void* d_out, int out_size, void* d_ws, size_t ws_size,
                              hipStream_t stream) {
    const float* obs = (const float*)d_in[0];
    const float* a0  = (const float*)d_in[1];
    const float* w1  = (const float*)d_in[2];
    const float* b1  = (const float*)d_in[3];
    const float* w2  = (const float*)d_in[4];
    const float* b2  = (const float*)d_in[5];
    const float* w3  = (const float*)d_in[6];
    const float* b3  = (const float*)d_in[7];

    float* out_a    = (float*)d_out;                 // [BN,16]
    float* out_logp = out_a + (size_t)BNROWS * 16;   // [BN]
    float* out_q    = out_logp + BNROWS;             // [BN]

    char* p = (char*)d_ws;
    ushort* pB1 = (ushort*)p; p += 24576 * 2;
    ushort* pB2 = (ushort*)p; p += 65536 * 2;
    ushort* pB3 = (ushort*)p; p += 65536 * 2;
    ushort* pB4 = (ushort*)p; p += 4096 * 2;
    float* abuf0 = (float*)p; p += (size_t)BNROWS * 16 * 4;
    float* abuf1 = (float*)p; p += (size_t)BNROWS * 16 * 4;
    float* scr   = (float*)p; p += (size_t)BNROWS * 16 * 4;
    float* logp  = (float*)p; p += (size_t)BNROWS * 4;
    float* qtmp  = (float*)p;

    prep_pack<<<78, 256, 0, stream>>>(w1, w2, pB1, pB2, pB3, pB4);

    const int MB = BNROWS / RB;   // 2048 blocks
    const int SB = 4096 / 4;      // 1024 blocks, 4 states (waves) each

    // step 1
    mlp_mfma<<<MB, 512, 0, stream>>>(obs, a0, b1, b2, w3, b3,
                                     pB1, pB2, pB3, pB4, scr, qtmp, 0);
    svgd6<<<SB, 256, 0, stream>>>(a0, scr, nullptr, logp, abuf0, 1);
    // step 2
    mlp_mfma<<<MB, 512, 0, stream>>>(obs, abuf0, b1, b2, w3, b3,
                                     pB1, pB2, pB3, pB4, scr, qtmp, 0);
    svgd6<<<SB, 256, 0, stream>>>(abuf0, scr, logp, logp, abuf1, 0);
    // step 3 (q of this step is the q_vals output)
    mlp_mfma<<<MB, 512, 0, stream>>>(obs, abuf1, b1, b2, w3, b3,
                                     pB1, pB2, pB3, pB4, scr, out_q, 1);
    svgd6<<<SB, 256, 0, stream>>>(abuf1, scr, logp, out_logp, out_a, 0);
}